// Round 4
// baseline (341.181 us; speedup 1.0000x reference)
//
#include <hip/hip_runtime.h>
#include <cstdint>

typedef unsigned short u16;
typedef __attribute__((ext_vector_type(8))) short bf16x8;
typedef __attribute__((ext_vector_type(4))) float f32x4;
typedef __attribute__((ext_vector_type(4))) unsigned short u16x4;

#define AS_G __attribute__((address_space(1)))
#define AS_L __attribute__((address_space(3)))

__device__ __forceinline__ void gl_lds16(const u16* g, u16* l) {
  // async global->LDS, 16B/lane; LDS dest = wave-uniform base + lane*16
  __builtin_amdgcn_global_load_lds((const AS_G unsigned int*)g, (AS_L unsigned int*)l, 16, 0, 0);
}
__device__ __forceinline__ float bf2f(u16 u) {
  union { unsigned int i; float f; } v; v.i = ((unsigned int)u) << 16; return v.f;
}
__device__ __forceinline__ u16 f2bf(float f) {
  union { float f; unsigned int i; } v; v.f = f;
  unsigned int x = v.i;
  return (u16)((x + 0x7fffu + ((x >> 16) & 1u)) >> 16);  // RNE
}

// ---------------- weight pre-transpose (fp32 src -> bf16 dst) ----------------
__global__ __launch_bounds__(256) void transpose_kernel(
    const float* __restrict__ s0, const float* __restrict__ s1, const float* __restrict__ s2,
    const float* __restrict__ s3, const float* __restrict__ s4, u16* __restrict__ wdst)
{
  const int id = blockIdx.y;
  const float* src; u16* dst; int rb, total;
  switch (id) {
    case 0:  src = s0; dst = wdst;           rb = 8;  total = 524288; break;
    case 1:  src = s1; dst = wdst + 524288;  rb = 8;  total = 524288; break;
    case 2:  src = s2; dst = wdst + 1048576; rb = 8;  total = 524288; break;
    case 3:  src = s3; dst = wdst + 1572864; rb = 11; total = 524288; break;
    default: src = s4; dst = wdst + 2097152; rb = 8;  total = 65536;  break;
  }
  const int o = blockIdx.x * 256 + threadIdx.x;
  if (o >= total) return;
  const int C_ = total >> rb;
  const int c = o >> rb, r = o & ((1 << rb) - 1);
  dst[o] = f2bf(src[r * C_ + c]);
}

// ---------------- QKV projection on the UNGATHERED 8192 rows ----------------
// 128x128 tile, 4 waves, double-buffered counted-vmcnt K-loop, fp32 inputs.
// R4 fixes vs R3 (which regressed 64.6 -> 85 us):
//  (a) A-staging map ar=t&127, kh=t>>7: each wave ds_writes one CONTIGUOUS
//      1KB span (was interleaved 16i / 4096+16i -> 5x bank conflicts).
//  (b) A_WRITE(nxt) moved AFTER the MFMA block: the vmcnt wait on next
//      chunk's A-loads no longer blocks current-chunk MFMA issue.
__global__ __launch_bounds__(256) void proj_kernel(
    const float* __restrict__ qf, const float* __restrict__ kf, const float* __restrict__ vf,
    const u16* __restrict__ wts, const float* __restrict__ bq, const float* __restrict__ bk,
    const float* __restrict__ bv, u16* __restrict__ Pq, u16* __restrict__ Pk,
    u16* __restrict__ Pv)
{
  __shared__ u16 lds[16384];            // buf b at [b*8192): A [0,4096)+B [4096,8192); epilogue: 64x136 per half
  const int t = threadIdx.x;
  const int w = t >> 6, lane = t & 63, quad = lane >> 4, lc = lane & 15;
  const int wy = w >> 1, wx = w & 1;
  // swizzle: same-by blocks (sharing the A slab) are XCD-local.
  const int flat = blockIdx.x + (blockIdx.y << 4);   // 0..1023
  const int tn = flat >> 6, by = flat & 63, z = blockIdx.z;
  const float* Af = ((z == 0) ? qf : (z == 1) ? kf : vf) + by * 32768;  // 128 rows x 256 f32
  const u16* BT = wts + z * 524288 + tn * 128 * 256;

  const int ar = t & 127, kh = t >> 7;  // A staging: row 0..127, k-half (16 f32)
  const float* Arow = Af + ar * 256 + kh * 16;

  const f32x4 fz = {0.f, 0.f, 0.f, 0.f};
  f32x4 acc[4][4];
#pragma unroll
  for (int i = 0; i < 4; ++i)
#pragma unroll
    for (int j = 0; j < 4; ++j) acc[i][j] = fz;

  f32x4 a4[4];
#define A_LOAD(ck) do {                                                \
    const float* p_ = Arow + (ck) * 32;                                \
    a4[0] = *(const f32x4*)(p_);      a4[1] = *(const f32x4*)(p_ + 4); \
    a4[2] = *(const f32x4*)(p_ + 8);  a4[3] = *(const f32x4*)(p_ + 12);\
  } while (0)
#define A_WRITE(b) do {                                                \
    bf16x8 lo_, hi_;                                                   \
    _Pragma("unroll")                                                  \
    for (int i_ = 0; i_ < 8; ++i_) {                                   \
      lo_[i_] = (short)f2bf(a4[i_ >> 2][i_ & 3]);                      \
      hi_[i_] = (short)f2bf(a4[2 + (i_ >> 2)][i_ & 3]);                \
    }                                                                  \
    *(bf16x8*)&lds[(b) * 8192 + (kh * 2 + 0) * 1024 + ar * 8] = lo_;   \
    *(bf16x8*)&lds[(b) * 8192 + (kh * 2 + 1) * 1024 + ar * 8] = hi_;   \
  } while (0)
#define B_STAGE(ck, b) do {                                            \
    const int ko_ = (ck) * 32 + w * 8;                                 \
    gl_lds16(BT + lane * 256 + ko_,        &lds[(b) * 8192 + 4096 + w * 1024]);       \
    gl_lds16(BT + (64 + lane) * 256 + ko_, &lds[(b) * 8192 + 4096 + w * 1024 + 512]); \
  } while (0)

  // prologue: chunk 0
  A_LOAD(0);
  B_STAGE(0, 0);
  A_WRITE(0);                           // compiler waits a4 (vmcnt), then cvt+ds_write

#pragma unroll
  for (int ck = 0; ck < 8; ++ck) {
    const int cur = ck & 1;
    if (ck < 7) {
      A_LOAD(ck + 1);                   // 4 vmem -> regs
      B_STAGE(ck + 1, cur ^ 1);         // 2 vmem -> LDS[nxt]
      asm volatile("s_waitcnt vmcnt(6) lgkmcnt(0)" ::: "memory");  // B(ck) landed; my ds ops drained
    } else {
      asm volatile("s_waitcnt vmcnt(0) lgkmcnt(0)" ::: "memory");
    }
    __builtin_amdgcn_s_barrier();       // buf[cur] complete for all waves
    asm volatile("" ::: "memory");
    const u16* Ab = &lds[cur * 8192];
    const u16* Bb = &lds[cur * 8192 + 4096];
    bf16x8 af[4], bfg[4];
#pragma unroll
    for (int mi = 0; mi < 4; ++mi)
      af[mi] = *(const bf16x8*)&Ab[quad * 1024 + (wy * 64 + mi * 16 + lc) * 8];
#pragma unroll
    for (int ni = 0; ni < 4; ++ni)
      bfg[ni] = *(const bf16x8*)&Bb[quad * 1024 + (wx * 64 + ni * 16 + lc) * 8];
    __builtin_amdgcn_s_setprio(1);
#pragma unroll
    for (int mi = 0; mi < 4; ++mi)
#pragma unroll
      for (int ni = 0; ni < 4; ++ni)
        acc[mi][ni] = __builtin_amdgcn_mfma_f32_16x16x32_bf16(af[mi], bfg[ni], acc[mi][ni], 0, 0, 0);
    __builtin_amdgcn_s_setprio(0);
    if (ck < 7) A_WRITE(cur ^ 1);       // after MFMA: a4 vmcnt-wait overlaps MFMA issue
    asm volatile("s_waitcnt lgkmcnt(0)" ::: "memory");   // my ds reads+writes done
    __builtin_amdgcn_s_barrier();       // buf[cur] freeable; A(nxt) visible
  }
#undef A_LOAD
#undef A_WRITE
#undef B_STAGE

  const float* bias = (z == 0) ? bq : (z == 1) ? bk : bv;
  u16* P = ((z == 0) ? Pq : (z == 1) ? Pk : Pv) + by * 262144;

  // Two 64-row epilogue passes; each uses only 64x136 u16 = 17408 B of LDS.
#pragma unroll
  for (int half = 0; half < 2; ++half) {
    __syncthreads();                     // prev pass reads / K-loop staging done
    if (wy == half) {
#pragma unroll
      for (int mi = 0; mi < 4; ++mi)
#pragma unroll
        for (int ni = 0; ni < 4; ++ni) {
          const int col = wx * 64 + ni * 16 + lc;
          const float bi = bias[tn * 128 + col];
#pragma unroll
          for (int r = 0; r < 4; ++r) {
            const int row = mi * 16 + quad * 4 + r;
            lds[row * 136 + col] = f2bf(acc[mi][ni][r] + bi);
          }
        }
    }
    __syncthreads();
#pragma unroll
    for (int p = 0; p < 4; ++p) {        // 256B-contiguous row segments, 16B/lane
      const int e = p * 2048 + t * 8;
      const int row = e >> 7, col0 = e & 127;
      *(bf16x8*)(P + (half * 64 + row) * 2048 + tn * 128 + col0) =
          *(const bf16x8*)&lds[row * 136 + col0];
    }
  }
}

// ---------------- Pv group-slab transpose (coalesced both sides) ----------------
__global__ __launch_bounds__(256) void vtrans_kernel(
    const u16* __restrict__ Pv, u16* __restrict__ VT)
{
  __shared__ u16 lT[4096];
  const int t = threadIdx.x;
  const int tile = blockIdx.x;          // 0..7
  const int g = blockIdx.y;             // 0..511
  const int q0 = (tile & 1) * 64, d0 = (tile >> 1) * 64;
  const u16* src = Pv + g * 32768;      // [q'=128][d=256]
  u16* dst = VT + g * 32768;            // [d=256][q'=128]
#pragma unroll
  for (int it = 0; it < 2; ++it) {
    const int e = it * 2048 + t * 8;
    const int lq = e >> 6, ld0 = e & 63;
    const bf16x8 v = *(const bf16x8*)(src + (q0 + lq) * 256 + d0 + ld0);
    const int kb = ((ld0 >> 3) + lq + (lq >> 3)) & 7;
    *(bf16x8*)&lT[lq * 64 + kb * 8] = v;
  }
  __syncthreads();
#pragma unroll
  for (int it = 0; it < 2; ++it) {
    const int e = it * 2048 + t * 8;
    const int ld = e >> 6, lq0 = e & 63;
    bf16x8 v;
#pragma unroll
    for (int i = 0; i < 8; ++i) {
      const int lq = lq0 + i;
      const int kb = ((ld >> 3) + lq + (lq >> 3)) & 7;
      v[i] = (short)lT[lq * 64 + kb * 8 + (ld & 7)];
    }
    *(bf16x8*)(dst + (d0 + ld) * 128 + q0 + lq0) = v;
  }
}

// ---------------- attention per (block, head) ----------------
__global__ __launch_bounds__(512) void attn_kernel(
    const u16* __restrict__ Pq, const u16* __restrict__ Pk,
    const u16* __restrict__ VT, u16* __restrict__ Obuf)
{
  __shared__ u16 lKV[16384];
  __shared__ u16 lP[16384];
  const int t = threadIdx.x;
  const int w = t >> 6, lane = t & 63, quad = lane >> 4, lc = lane & 15;
  const int h = blockIdx.x, bb = blockIdx.y;
  const int b = bb / 15, n = bb % 15;
  const int m0 = w * 16;
  const int r0 = b * 1024 + n * 64 + h * 16;
  const u16* Qb = Pq + r0 * 2048;
  const u16* Kb = Pk + r0 * 2048;
  const u16* Vb = VT + (b * 64 + n * 4 + h) * 32768;
  const f32x4 fz = {0.f, 0.f, 0.f, 0.f};

  bf16x8 aq[8];
#pragma unroll
  for (int kc = 0; kc < 8; ++kc)
    aq[kc] = *(const bf16x8*)(Qb + (m0 + lc) * 256 + kc * 32 + quad * 8);

  f32x4 s[8];
  for (int hk = 0; hk < 2; ++hk) {
    __syncthreads();
#pragma unroll
    for (int jj = 0; jj < 4; ++jj)
      gl_lds16(Kb + (hk * 64 + lane) * 256 + w * 32 + jj * 8, &lKV[w * 2048 + jj * 512]);
    __syncthreads();
    __builtin_amdgcn_s_setprio(1);
#pragma unroll
    for (int ntl = 0; ntl < 4; ++ntl) {
      const int nt = hk * 4 + ntl;
      s[nt] = fz;
#pragma unroll
      for (int kc = 0; kc < 8; ++kc) {
        const bf16x8 bfr = *(const bf16x8*)&lKV[kc * 2048 + quad * 512 + (ntl * 16 + lc) * 8];
        s[nt] = __builtin_amdgcn_mfma_f32_16x16x32_bf16(aq[kc], bfr, s[nt], 0, 0, 0);
      }
    }
    __builtin_amdgcn_s_setprio(0);
  }

  const float scale = 0.0625f;
#pragma unroll
  for (int r = 0; r < 4; ++r) {
    float mx = -3.0e38f;
#pragma unroll
    for (int nt = 0; nt < 8; ++nt) mx = fmaxf(mx, s[nt][r]);
    mx = fmaxf(mx, __shfl_xor(mx, 1)); mx = fmaxf(mx, __shfl_xor(mx, 2));
    mx = fmaxf(mx, __shfl_xor(mx, 4)); mx = fmaxf(mx, __shfl_xor(mx, 8));
    mx *= scale;
    float sm = 0.0f;
#pragma unroll
    for (int nt = 0; nt < 8; ++nt) {
      const float e = __expf(s[nt][r] * scale - mx);
      s[nt][r] = e; sm += e;
    }
    sm += __shfl_xor(sm, 1); sm += __shfl_xor(sm, 2);
    sm += __shfl_xor(sm, 4); sm += __shfl_xor(sm, 8);
    const float inv = 1.0f / sm;
    const int q = m0 + quad * 4 + r;
#pragma unroll
    for (int nt = 0; nt < 8; ++nt) {
      const int k = nt * 16 + lc;
      lP[(k >> 5) * 4096 + ((k >> 3) & 3) * 1024 + q * 8 + (k & 7)] = f2bf(s[nt][r] * inv);
    }
  }
  __syncthreads();

  bf16x8 ap[4];
#pragma unroll
  for (int kc2 = 0; kc2 < 4; ++kc2)
    ap[kc2] = *(const bf16x8*)&lP[kc2 * 4096 + quad * 1024 + (m0 + lc) * 8];

  f32x4 o[16];
#pragma unroll
  for (int nt = 0; nt < 16; ++nt) o[nt] = fz;

  for (int hk = 0; hk < 2; ++hk) {
    if (hk) __syncthreads();
#pragma unroll
    for (int jj = 0; jj < 4; ++jj) {
      const int i = w * 4 + jj;
      const int kc2l = i >> 4, cb = (i >> 2) & 3, db = (i & 3) * 64;
      gl_lds16(Vb + (db + lane) * 128 + (hk * 2 + kc2l) * 32 + cb * 8,
               &lKV[kc2l * 8192 + cb * 2048 + db * 8]);
    }
    __syncthreads();
    __builtin_amdgcn_s_setprio(1);
#pragma unroll
    for (int nt = 0; nt < 16; ++nt)
#pragma unroll
      for (int kc2l = 0; kc2l < 2; ++kc2l) {
        const bf16x8 bfr = *(const bf16x8*)&lKV[kc2l * 8192 + quad * 2048 + (nt * 16 + lc) * 8];
        o[nt] = __builtin_amdgcn_mfma_f32_16x16x32_bf16(ap[hk * 2 + kc2l], bfr, o[nt], 0, 0, 0);
      }
    __builtin_amdgcn_s_setprio(0);
  }

  u16* Ob = Obuf + bb * 262144 + h * 32768;   // gathered output (separate buffer)
#pragma unroll
  for (int nt = 0; nt < 16; ++nt)
#pragma unroll
    for (int r = 0; r < 4; ++r) {
      const int q = m0 + quad * 4 + r;
      Ob[q * 256 + nt * 16 + lc] = f2bf(o[nt][r]);
    }
}

// ---------------- 64x256-tile GEMM (4 waves x 64 cols), optional split-K ----------------
// Full-N tile (N=256) so A is read ONCE. Counted-vmcnt double-buffered
// staging; per chunk/wave 1 A + 4 B gl_lds16 = 5 vmem -> vmcnt(5).
// mode 0: raw fp32 partial store to out + kz*3932160 (Wo split-K path).
// mode 1: bias + bf16 residual epilogue -> fp32 out (FF path, gridDim.z == 1).
__global__ __launch_bounds__(256) void gemm64_kernel(
    const u16* __restrict__ A, const u16* __restrict__ BT, const float* __restrict__ bias,
    const u16* __restrict__ residb, float* __restrict__ out, int Ktot, int lda, int mode)
{
  __shared__ u16 lA[2][2048];           // [ks=4][64 rows][8]
  __shared__ u16 lB[2][8192];           // [ks=4][256 rows][8]
  const int t = threadIdx.x;
  const int w = t >> 6, lane = t & 63, quad = lane >> 4, lc = lane & 15;
  const int bb = blockIdx.x, kz = blockIdx.z;
  const int kslice = Ktot / gridDim.z;
  const int k0 = kz * kslice;
  const u16* A0 = A + bb * 64 * lda + k0;
  const u16* BT0 = BT + k0;

  const f32x4 fz = {0.f, 0.f, 0.f, 0.f};
  f32x4 acc[4][4];
#pragma unroll
  for (int i = 0; i < 4; ++i)
#pragma unroll
    for (int j = 0; j < 4; ++j) acc[i][j] = fz;

#define G64_STAGE(ck, b) do {                                          \
    const int ko_ = (ck) * 32 + w * 8;                                 \
    gl_lds16(A0 + lane * lda + ko_, &lA[b][w * 512]);                  \
    _Pragma("unroll")                                                  \
    for (int sg_ = 0; sg_ < 4; ++sg_)                                  \
      gl_lds16(BT0 + (sg_ * 64 + lane) * Ktot + ko_,                   \
               &lB[b][w * 2048 + sg_ * 512]);                          \
  } while (0)

  const int nck = kslice >> 5;
  G64_STAGE(0, 0);
  for (int ck = 0; ck < nck; ++ck) {
    const int cur = ck & 1;
    if (ck < nck - 1) {
      G64_STAGE(ck + 1, cur ^ 1);
      asm volatile("s_waitcnt vmcnt(5)" ::: "memory");   // chunk-ck loads landed; prefetch in flight
    } else {
      asm volatile("s_waitcnt vmcnt(0)" ::: "memory");
    }
    __builtin_amdgcn_s_barrier();
    asm volatile("" ::: "memory");
    bf16x8 af[4], bfg[4];
#pragma unroll
    for (int mi = 0; mi < 4; ++mi)
      af[mi] = *(const bf16x8*)&lA[cur][quad * 512 + (mi * 16 + lc) * 8];
#pragma unroll
    for (int ni = 0; ni < 4; ++ni) {
      const int cl = w * 64 + ni * 16 + lc;
      bfg[ni] = *(const bf16x8*)&lB[cur][quad * 2048 + cl * 8];
    }
    __builtin_amdgcn_s_setprio(1);
#pragma unroll
    for (int mi = 0; mi < 4; ++mi)
#pragma unroll
      for (int ni = 0; ni < 4; ++ni)
        acc[mi][ni] = __builtin_amdgcn_mfma_f32_16x16x32_bf16(af[mi], bfg[ni], acc[mi][ni], 0, 0, 0);
    __builtin_amdgcn_s_setprio(0);
    asm volatile("s_waitcnt lgkmcnt(0)" ::: "memory");
    __builtin_amdgcn_s_barrier();
  }
#undef G64_STAGE

  if (mode == 0) {
    float* O = out + kz * 3932160 + bb * 64 * 256;
#pragma unroll
    for (int mi = 0; mi < 4; ++mi)
#pragma unroll
      for (int ni = 0; ni < 4; ++ni) {
        const int cg = w * 64 + ni * 16 + lc;
#pragma unroll
        for (int r = 0; r < 4; ++r)
          O[(mi * 16 + quad * 4 + r) * 256 + cg] = acc[mi][ni][r];
      }
  } else {
#pragma unroll
    for (int mi = 0; mi < 4; ++mi)
#pragma unroll
      for (int ni = 0; ni < 4; ++ni) {
        const int cg = w * 64 + ni * 16 + lc;
        const float bi = bias[cg];
#pragma unroll
        for (int r = 0; r < 4; ++r) {
          const int rl = mi * 16 + quad * 4 + r;
          const float res = bf2f(residb[(bb * 64 + rl) * 256 + cg]);
          out[(bb * 64 + rl) * 256 + cg] = acc[mi][ni][r] + bi + res;
        }
      }
  }
}

// ---------------- fused split-K reduce + bias + value-resid + LN1 -> bf16 ----------------
__global__ __launch_bounds__(256) void reduce_ln_kernel(
    const float* __restrict__ part, const float* __restrict__ bias,
    const float* __restrict__ value, const float* __restrict__ gam,
    const float* __restrict__ bet, u16* __restrict__ dstb)
{
  const int t = threadIdx.x, w = t >> 6, lane = t & 63;
  const int row = blockIdx.x * 4 + w;
  const int e = row * 256 + lane * 4;
  const int col = lane * 4;
  const int bb = row >> 7, rl = row & 127, b = bb / 15, n = bb % 15;
  f32x4 s = *(const f32x4*)(part + e);
#pragma unroll
  for (int p = 1; p < 4; ++p) {
    const f32x4 v = *(const f32x4*)(part + p * 3932160 + e);
#pragma unroll
    for (int i = 0; i < 4; ++i) s[i] += v[i];
  }
  const f32x4 bi = *(const f32x4*)(bias + col);
  const f32x4 rv = *(const f32x4*)(value + (b * 1024 + n * 64 + rl) * 256 + col);
#pragma unroll
  for (int i = 0; i < 4; ++i) s[i] += bi[i] + rv[i];
  float sum = s[0] + s[1] + s[2] + s[3];
  float sq = s[0] * s[0] + s[1] * s[1] + s[2] * s[2] + s[3] * s[3];
#pragma unroll
  for (int m = 1; m < 64; m <<= 1) { sum += __shfl_xor(sum, m); sq += __shfl_xor(sq, m); }
  const float mean = sum * (1.0f / 256.0f);
  const float rs = rsqrtf(sq * (1.0f / 256.0f) - mean * mean + 1e-5f);
  const f32x4 g4 = *(const f32x4*)(gam + col);
  const f32x4 b4 = *(const f32x4*)(bet + col);
  u16x4 ob;
#pragma unroll
  for (int i = 0; i < 4; ++i) ob[i] = f2bf((s[i] - mean) * rs * g4[i] + b4[i]);
  *(u16x4*)(dstb + row * 256 + lane * 4) = ob;
}

// ---------------- layernorm (one wave per 256-wide row) ----------------
__global__ __launch_bounds__(256) void ln_kernel(
    const float* __restrict__ src, const float* __restrict__ gam, const float* __restrict__ bet,
    u16* __restrict__ dstb, float* __restrict__ dstf, int mode)
{
  const int t = threadIdx.x, w = t >> 6, lane = t & 63;
  const int row = blockIdx.x * 4 + w;
  const f32x4 v = *(const f32x4*)(src + row * 256 + lane * 4);
  float sum = v[0] + v[1] + v[2] + v[3];
  float sq = v[0] * v[0] + v[1] * v[1] + v[2] * v[2] + v[3] * v[3];
#pragma unroll
  for (int m = 1; m < 64; m <<= 1) { sum += __shfl_xor(sum, m); sq += __shfl_xor(sq, m); }
  const float mean = sum * (1.0f / 256.0f);
  const float rs = rsqrtf(sq * (1.0f / 256.0f) - mean * mean + 1e-5f);
  const f32x4 g4 = *(const f32x4*)(gam + lane * 4);
  const f32x4 b4 = *(const f32x4*)(bet + lane * 4);
  f32x4 o;
#pragma unroll
  for (int i = 0; i < 4; ++i)
    o[i] = (v[i] - mean) * rs * g4[i] + b4[i];
  if (mode == 0) {
    u16x4 ob;
#pragma unroll
    for (int i = 0; i < 4; ++i) ob[i] = f2bf(o[i]);
    *(u16x4*)(dstb + row * 256 + lane * 4) = ob;
  } else {
    const int bbq = row >> 7, r = row & 127, b = bbq / 15, n = bbq % 15;
    const bool valid = (n == 0) ? (r < 96) : ((n == 14) ? (r >= 32) : (r >= 32 && r < 96));
    if (valid)
      *(f32x4*)(dstf + ((b << 10) + n * 64 + r) * 256 + lane * 4) = o;
  }
}

extern "C" void kernel_launch(void* const* d_in, const int* in_sizes, int n_in,
                              void* d_out, int out_size, void* d_ws, size_t ws_size,
                              hipStream_t stream) {
  (void)in_sizes; (void)n_in; (void)out_size; (void)ws_size;
  const float* query = (const float*)d_in[0];
  const float* key   = (const float*)d_in[1];
  const float* value = (const float*)d_in[2];
  const float* Wq  = (const float*)d_in[3];
  const float* bq  = (const float*)d_in[4];
  const float* Wk  = (const float*)d_in[5];
  const float* bk  = (const float*)d_in[6];
  const float* Wv  = (const float*)d_in[7];
  const float* bv  = (const float*)d_in[8];
  const float* Wo  = (const float*)d_in[9];
  const float* bo  = (const float*)d_in[10];
  const float* g1  = (const float*)d_in[11];
  const float* b1  = (const float*)d_in[12];
  const float* Wff = (const float*)d_in[13];
  const float* bff = (const float*)d_in[14];
  const float* g2  = (const float*)d_in[15];
  const float* b2  = (const float*)d_in[16];

  // Workspace layout (proj reads fp32 inputs directly):
  u16* ws  = (u16*)d_ws;
  u16* WT  = ws;                      // [0, 2162688)
  u16* Pq  = ws + 8454144;            // 16,777,216 each (8192x2048 bf16)
  u16* Pk  = ws + 25231360;
  u16* VT  = ws + 42008576;           // 512 groups x [d=256][q'=128]
  u16* Obuf = ws + 58785792;          // 31,457,280 (gathered 15360x2048)
  u16* Pv  = Obuf;                    // first 16,777,216 of Obuf (dead before attn writes O)
  float* part = (float*)(ws + 8454144);   // 15,728,640 f32 over Pq+Pk (dead after attn)
  u16* xbuf   = ws + 49872896;            // 3,932,160 u16, within VT region (dead after attn)
  float* tmp2 = (float*)(ws + 58785792);  // over Obuf (dead after Wo gemm)

  transpose_kernel<<<dim3(2048, 5), 256, 0, stream>>>(Wq, Wk, Wv, Wo, Wff, WT);
  // Single proj pass over fp32 q/k/v on the original 8192 rows.
  proj_kernel<<<dim3(16, 64, 3), 256, 0, stream>>>(query, key, value, WT, bq, bk, bv, Pq, Pk, Pv);
  vtrans_kernel<<<dim3(8, 512), 256, 0, stream>>>(Pv, VT);
  attn_kernel<<<dim3(8, 120), 512, 0, stream>>>(Pq, Pk, VT, Obuf);
  // Wo GEMM: 64x256 tiles, split-K=4 -> partials; fused reduce+LN1 consumes them.
  gemm64_kernel<<<dim3(240, 1, 4), 256, 0, stream>>>(Obuf, WT + 1572864, nullptr, nullptr, part, 2048, 2048, 0);
  reduce_ln_kernel<<<3840, 256, 0, stream>>>(part, bo, value, g1, b1, xbuf);
  // FF GEMM: 64x256 tiles, fused bias + residual epilogue.
  gemm64_kernel<<<dim3(240, 1, 1), 256, 0, stream>>>(xbuf, WT + 2097152, bff, xbuf, tmp2, 256, 256, 1);
  ln_kernel<<<3840, 256, 0, stream>>>(tmp2, g2, b2, nullptr, (float*)d_out, 1);
}

// Round 5
// 316.697 us; speedup vs baseline: 1.0773x; 1.0773x over previous
//
#include <hip/hip_runtime.h>
#include <cstdint>

typedef unsigned short u16;
typedef __attribute__((ext_vector_type(8))) short bf16x8;
typedef __attribute__((ext_vector_type(4))) float f32x4;
typedef __attribute__((ext_vector_type(4))) unsigned short u16x4;

#define AS_G __attribute__((address_space(1)))
#define AS_L __attribute__((address_space(3)))

__device__ __forceinline__ void gl_lds16(const u16* g, u16* l) {
  // async global->LDS, 16B/lane; LDS dest = wave-uniform base + lane*16
  __builtin_amdgcn_global_load_lds((const AS_G unsigned int*)g, (AS_L unsigned int*)l, 16, 0, 0);
}
__device__ __forceinline__ float bf2f(u16 u) {
  union { unsigned int i; float f; } v; v.i = ((unsigned int)u) << 16; return v.f;
}
__device__ __forceinline__ u16 f2bf(float f) {
  union { float f; unsigned int i; } v; v.f = f;
  unsigned int x = v.i;
  return (u16)((x + 0x7fffu + ((x >> 16) & 1u)) >> 16);  // RNE
}

// ---------------- fp32 -> bf16 convert of q/k/v ----------------
__global__ __launch_bounds__(256) void convert_kernel(
    const float* __restrict__ q, const float* __restrict__ k, const float* __restrict__ v,
    u16* __restrict__ qb, u16* __restrict__ kb, u16* __restrict__ vb)
{
  const int id = blockIdx.y;
  const float* s = (id == 0) ? q : (id == 1) ? k : v;
  u16* d = (id == 0) ? qb : (id == 1) ? kb : vb;
  const int o = (blockIdx.x * 256 + threadIdx.x) * 4;
  const f32x4 x = *(const f32x4*)(s + o);
  u16x4 y;
#pragma unroll
  for (int i = 0; i < 4; ++i) y[i] = f2bf(x[i]);
  *(u16x4*)(d + o) = y;
}

// ---------------- weight pre-transpose (fp32 src -> bf16 dst) ----------------
__global__ __launch_bounds__(256) void transpose_kernel(
    const float* __restrict__ s0, const float* __restrict__ s1, const float* __restrict__ s2,
    const float* __restrict__ s3, const float* __restrict__ s4, u16* __restrict__ wdst)
{
  const int id = blockIdx.y;
  const float* src; u16* dst; int rb, total;
  switch (id) {
    case 0:  src = s0; dst = wdst;           rb = 8;  total = 524288; break;
    case 1:  src = s1; dst = wdst + 524288;  rb = 8;  total = 524288; break;
    case 2:  src = s2; dst = wdst + 1048576; rb = 8;  total = 524288; break;
    case 3:  src = s3; dst = wdst + 1572864; rb = 11; total = 524288; break;
    default: src = s4; dst = wdst + 2097152; rb = 8;  total = 65536;  break;
  }
  const int o = blockIdx.x * 256 + threadIdx.x;
  if (o >= total) return;
  const int C_ = total >> rb;
  const int c = o >> rb, r = o & ((1 << rb) - 1);
  dst[o] = f2bf(src[r * C_ + c]);
}

// ---------------- QKV projection on the UNGATHERED 8192 rows ----------------
// EXACT R2 structure (best measured: 64.6 us): 128x128 tile, 4 waves,
// pure gl_lds16 staging for A and B, double-buffered counted-vmcnt(4),
// XCD swizzle (A-slab sharers XCD-local), two-pass 64-row epilogue
// (LDS 32768 B). R3/R4's fp32-direct reg-staged A is abandoned per the
// pre-committed falsifier: conflicts fixed but proj stayed >75 us.
__global__ __launch_bounds__(256) void proj_kernel(
    const u16* __restrict__ qb, const u16* __restrict__ kb, const u16* __restrict__ vb,
    const u16* __restrict__ wts, const float* __restrict__ bq, const float* __restrict__ bk,
    const float* __restrict__ bv, u16* __restrict__ Pq, u16* __restrict__ Pk,
    u16* __restrict__ Pv)
{
  __shared__ u16 lds[16384];            // buf b at [b*8192): A [0,4096)+B [4096,8192); epilogue: 64x136 per half
  const int t = threadIdx.x;
  const int w = t >> 6, lane = t & 63, quad = lane >> 4, lc = lane & 15;
  const int wy = w >> 1, wx = w & 1;
  // swizzle: same-by blocks (sharing the A slab) are XCD-local.
  const int flat = blockIdx.x + (blockIdx.y << 4);   // 0..1023
  const int tn = flat >> 6, by = flat & 63, z = blockIdx.z;
  const u16* A0 = ((z == 0) ? qb : (z == 1) ? kb : vb) + by * 32768;   // 128 rows x 256
  const u16* BT = wts + z * 524288 + tn * 128 * 256;

  const f32x4 fz = {0.f, 0.f, 0.f, 0.f};
  f32x4 acc[4][4];
#pragma unroll
  for (int i = 0; i < 4; ++i)
#pragma unroll
    for (int j = 0; j < 4; ++j) acc[i][j] = fz;

#define PROJ_STAGE(ck, b) do {                                         \
    const int ko_ = (ck) * 32 + w * 8;                                 \
    u16* Lb_ = &lds[(b) * 8192];                                       \
    gl_lds16(A0 + lane * 256 + ko_,        Lb_ + w * 1024);            \
    gl_lds16(A0 + (64 + lane) * 256 + ko_, Lb_ + w * 1024 + 512);      \
    gl_lds16(BT + lane * 256 + ko_,        Lb_ + 4096 + w * 1024);     \
    gl_lds16(BT + (64 + lane) * 256 + ko_, Lb_ + 4096 + w * 1024 + 512); \
  } while (0)

  PROJ_STAGE(0, 0);
#pragma unroll
  for (int ck = 0; ck < 8; ++ck) {
    const int cur = ck & 1;
    if (ck < 7) {
      PROJ_STAGE(ck + 1, cur ^ 1);
      asm volatile("s_waitcnt vmcnt(4)" ::: "memory");   // own chunk-ck loads landed; prefetch stays in flight
    } else {
      asm volatile("s_waitcnt vmcnt(0)" ::: "memory");
    }
    __builtin_amdgcn_s_barrier();                        // all waves' chunk-ck loads landed
    asm volatile("" ::: "memory");
    const u16* Ab = &lds[cur * 8192];
    const u16* Bb = &lds[cur * 8192 + 4096];
    bf16x8 af[4], bfg[4];
#pragma unroll
    for (int mi = 0; mi < 4; ++mi)
      af[mi] = *(const bf16x8*)&Ab[quad * 1024 + (wy * 64 + mi * 16 + lc) * 8];
#pragma unroll
    for (int ni = 0; ni < 4; ++ni)
      bfg[ni] = *(const bf16x8*)&Bb[quad * 1024 + (wx * 64 + ni * 16 + lc) * 8];
#pragma unroll
    for (int mi = 0; mi < 4; ++mi)
#pragma unroll
      for (int ni = 0; ni < 4; ++ni)
        acc[mi][ni] = __builtin_amdgcn_mfma_f32_16x16x32_bf16(af[mi], bfg[ni], acc[mi][ni], 0, 0, 0);
    asm volatile("s_waitcnt lgkmcnt(0)" ::: "memory");   // all ds_reads of buf[cur] done
    __builtin_amdgcn_s_barrier();                        // safe to overwrite buf[cur] next iter
  }
#undef PROJ_STAGE

  const float* bias = (z == 0) ? bq : (z == 1) ? bk : bv;
  u16* P = ((z == 0) ? Pq : (z == 1) ? Pk : Pv) + by * 262144;

  // Two 64-row epilogue passes; each uses only 64x136 u16 = 17408 B of LDS.
#pragma unroll
  for (int half = 0; half < 2; ++half) {
    __syncthreads();                     // prev pass reads / K-loop staging done
    if (wy == half) {
#pragma unroll
      for (int mi = 0; mi < 4; ++mi)
#pragma unroll
        for (int ni = 0; ni < 4; ++ni) {
          const int col = wx * 64 + ni * 16 + lc;
          const float bi = bias[tn * 128 + col];
#pragma unroll
          for (int r = 0; r < 4; ++r) {
            const int row = mi * 16 + quad * 4 + r;
            lds[row * 136 + col] = f2bf(acc[mi][ni][r] + bi);
          }
        }
    }
    __syncthreads();
#pragma unroll
    for (int p = 0; p < 4; ++p) {        // 256B-contiguous row segments, 16B/lane
      const int e = p * 2048 + t * 8;
      const int row = e >> 7, col0 = e & 127;
      *(bf16x8*)(P + (half * 64 + row) * 2048 + tn * 128 + col0) =
          *(const bf16x8*)&lds[row * 136 + col0];
    }
  }
}

// ---------------- Pv group-slab transpose (coalesced both sides) ----------------
__global__ __launch_bounds__(256) void vtrans_kernel(
    const u16* __restrict__ Pv, u16* __restrict__ VT)
{
  __shared__ u16 lT[4096];
  const int t = threadIdx.x;
  const int tile = blockIdx.x;          // 0..7
  const int g = blockIdx.y;             // 0..511
  const int q0 = (tile & 1) * 64, d0 = (tile >> 1) * 64;
  const u16* src = Pv + g * 32768;      // [q'=128][d=256]
  u16* dst = VT + g * 32768;            // [d=256][q'=128]
#pragma unroll
  for (int it = 0; it < 2; ++it) {
    const int e = it * 2048 + t * 8;
    const int lq = e >> 6, ld0 = e & 63;
    const bf16x8 v = *(const bf16x8*)(src + (q0 + lq) * 256 + d0 + ld0);
    const int kb = ((ld0 >> 3) + lq + (lq >> 3)) & 7;
    *(bf16x8*)&lT[lq * 64 + kb * 8] = v;
  }
  __syncthreads();
#pragma unroll
  for (int it = 0; it < 2; ++it) {
    const int e = it * 2048 + t * 8;
    const int ld = e >> 6, lq0 = e & 63;
    bf16x8 v;
#pragma unroll
    for (int i = 0; i < 8; ++i) {
      const int lq = lq0 + i;
      const int kb = ((ld >> 3) + lq + (lq >> 3)) & 7;
      v[i] = (short)lT[lq * 64 + kb * 8 + (ld & 7)];
    }
    *(bf16x8*)(dst + (d0 + ld) * 128 + q0 + lq0) = v;
  }
}

// ---------------- attention per (block, head) ----------------
__global__ __launch_bounds__(512) void attn_kernel(
    const u16* __restrict__ Pq, const u16* __restrict__ Pk,
    const u16* __restrict__ VT, u16* __restrict__ Obuf)
{
  __shared__ u16 lKV[16384];
  __shared__ u16 lP[16384];
  const int t = threadIdx.x;
  const int w = t >> 6, lane = t & 63, quad = lane >> 4, lc = lane & 15;
  const int h = blockIdx.x, bb = blockIdx.y;
  const int b = bb / 15, n = bb % 15;
  const int m0 = w * 16;
  const int r0 = b * 1024 + n * 64 + h * 16;
  const u16* Qb = Pq + r0 * 2048;
  const u16* Kb = Pk + r0 * 2048;
  const u16* Vb = VT + (b * 64 + n * 4 + h) * 32768;
  const f32x4 fz = {0.f, 0.f, 0.f, 0.f};

  bf16x8 aq[8];
#pragma unroll
  for (int kc = 0; kc < 8; ++kc)
    aq[kc] = *(const bf16x8*)(Qb + (m0 + lc) * 256 + kc * 32 + quad * 8);

  f32x4 s[8];
  for (int hk = 0; hk < 2; ++hk) {
    __syncthreads();
#pragma unroll
    for (int jj = 0; jj < 4; ++jj)
      gl_lds16(Kb + (hk * 64 + lane) * 256 + w * 32 + jj * 8, &lKV[w * 2048 + jj * 512]);
    __syncthreads();
#pragma unroll
    for (int ntl = 0; ntl < 4; ++ntl) {
      const int nt = hk * 4 + ntl;
      s[nt] = fz;
#pragma unroll
      for (int kc = 0; kc < 8; ++kc) {
        const bf16x8 bfr = *(const bf16x8*)&lKV[kc * 2048 + quad * 512 + (ntl * 16 + lc) * 8];
        s[nt] = __builtin_amdgcn_mfma_f32_16x16x32_bf16(aq[kc], bfr, s[nt], 0, 0, 0);
      }
    }
  }

  const float scale = 0.0625f;
#pragma unroll
  for (int r = 0; r < 4; ++r) {
    float mx = -3.0e38f;
#pragma unroll
    for (int nt = 0; nt < 8; ++nt) mx = fmaxf(mx, s[nt][r]);
    mx = fmaxf(mx, __shfl_xor(mx, 1)); mx = fmaxf(mx, __shfl_xor(mx, 2));
    mx = fmaxf(mx, __shfl_xor(mx, 4)); mx = fmaxf(mx, __shfl_xor(mx, 8));
    mx *= scale;
    float sm = 0.0f;
#pragma unroll
    for (int nt = 0; nt < 8; ++nt) {
      const float e = __expf(s[nt][r] * scale - mx);
      s[nt][r] = e; sm += e;
    }
    sm += __shfl_xor(sm, 1); sm += __shfl_xor(sm, 2);
    sm += __shfl_xor(sm, 4); sm += __shfl_xor(sm, 8);
    const float inv = 1.0f / sm;
    const int q = m0 + quad * 4 + r;
#pragma unroll
    for (int nt = 0; nt < 8; ++nt) {
      const int k = nt * 16 + lc;
      lP[(k >> 5) * 4096 + ((k >> 3) & 3) * 1024 + q * 8 + (k & 7)] = f2bf(s[nt][r] * inv);
    }
  }
  __syncthreads();

  bf16x8 ap[4];
#pragma unroll
  for (int kc2 = 0; kc2 < 4; ++kc2)
    ap[kc2] = *(const bf16x8*)&lP[kc2 * 4096 + quad * 1024 + (m0 + lc) * 8];

  f32x4 o[16];
#pragma unroll
  for (int nt = 0; nt < 16; ++nt) o[nt] = fz;

  for (int hk = 0; hk < 2; ++hk) {
    if (hk) __syncthreads();
#pragma unroll
    for (int jj = 0; jj < 4; ++jj) {
      const int i = w * 4 + jj;
      const int kc2l = i >> 4, cb = (i >> 2) & 3, db = (i & 3) * 64;
      gl_lds16(Vb + (db + lane) * 128 + (hk * 2 + kc2l) * 32 + cb * 8,
               &lKV[kc2l * 8192 + cb * 2048 + db * 8]);
    }
    __syncthreads();
#pragma unroll
    for (int nt = 0; nt < 16; ++nt)
#pragma unroll
      for (int kc2l = 0; kc2l < 2; ++kc2l) {
        const bf16x8 bfr = *(const bf16x8*)&lKV[kc2l * 8192 + quad * 2048 + (nt * 16 + lc) * 8];
        o[nt] = __builtin_amdgcn_mfma_f32_16x16x32_bf16(ap[hk * 2 + kc2l], bfr, o[nt], 0, 0, 0);
      }
  }

  u16* Ob = Obuf + bb * 262144 + h * 32768;   // gathered output (separate buffer)
#pragma unroll
  for (int nt = 0; nt < 16; ++nt)
#pragma unroll
    for (int r = 0; r < 4; ++r) {
      const int q = m0 + quad * 4 + r;
      Ob[q * 256 + nt * 16 + lc] = f2bf(o[nt][r]);
    }
}

// ---------------- 64x256-tile GEMM (4 waves x 64 cols), optional split-K ----------------
// Full-N tile (N=256) so A is read ONCE. Counted-vmcnt double-buffered
// staging; per chunk/wave 1 A + 4 B gl_lds16 = 5 vmem -> vmcnt(5).
// mode 0: raw fp32 partial store to out + kz*3932160 (Wo split-K path).
// mode 1: bias + bf16 residual epilogue -> fp32 out (FF path, gridDim.z == 1).
__global__ __launch_bounds__(256) void gemm64_kernel(
    const u16* __restrict__ A, const u16* __restrict__ BT, const float* __restrict__ bias,
    const u16* __restrict__ residb, float* __restrict__ out, int Ktot, int lda, int mode)
{
  __shared__ u16 lA[2][2048];           // [ks=4][64 rows][8]
  __shared__ u16 lB[2][8192];           // [ks=4][256 rows][8]
  const int t = threadIdx.x;
  const int w = t >> 6, lane = t & 63, quad = lane >> 4, lc = lane & 15;
  const int bb = blockIdx.x, kz = blockIdx.z;
  const int kslice = Ktot / gridDim.z;
  const int k0 = kz * kslice;
  const u16* A0 = A + bb * 64 * lda + k0;
  const u16* BT0 = BT + k0;

  const f32x4 fz = {0.f, 0.f, 0.f, 0.f};
  f32x4 acc[4][4];
#pragma unroll
  for (int i = 0; i < 4; ++i)
#pragma unroll
    for (int j = 0; j < 4; ++j) acc[i][j] = fz;

#define G64_STAGE(ck, b) do {                                          \
    const int ko_ = (ck) * 32 + w * 8;                                 \
    gl_lds16(A0 + lane * lda + ko_, &lA[b][w * 512]);                  \
    _Pragma("unroll")                                                  \
    for (int sg_ = 0; sg_ < 4; ++sg_)                                  \
      gl_lds16(BT0 + (sg_ * 64 + lane) * Ktot + ko_,                   \
               &lB[b][w * 2048 + sg_ * 512]);                          \
  } while (0)

  const int nck = kslice >> 5;
  G64_STAGE(0, 0);
  for (int ck = 0; ck < nck; ++ck) {
    const int cur = ck & 1;
    if (ck < nck - 1) {
      G64_STAGE(ck + 1, cur ^ 1);
      asm volatile("s_waitcnt vmcnt(5)" ::: "memory");   // chunk-ck loads landed; prefetch in flight
    } else {
      asm volatile("s_waitcnt vmcnt(0)" ::: "memory");
    }
    __builtin_amdgcn_s_barrier();
    asm volatile("" ::: "memory");
    bf16x8 af[4], bfg[4];
#pragma unroll
    for (int mi = 0; mi < 4; ++mi)
      af[mi] = *(const bf16x8*)&lA[cur][quad * 512 + (mi * 16 + lc) * 8];
#pragma unroll
    for (int ni = 0; ni < 4; ++ni) {
      const int cl = w * 64 + ni * 16 + lc;
      bfg[ni] = *(const bf16x8*)&lB[cur][quad * 2048 + cl * 8];
    }
#pragma unroll
    for (int mi = 0; mi < 4; ++mi)
#pragma unroll
      for (int ni = 0; ni < 4; ++ni)
        acc[mi][ni] = __builtin_amdgcn_mfma_f32_16x16x32_bf16(af[mi], bfg[ni], acc[mi][ni], 0, 0, 0);
    asm volatile("s_waitcnt lgkmcnt(0)" ::: "memory");
    __builtin_amdgcn_s_barrier();
  }
#undef G64_STAGE

  if (mode == 0) {
    float* O = out + kz * 3932160 + bb * 64 * 256;
#pragma unroll
    for (int mi = 0; mi < 4; ++mi)
#pragma unroll
      for (int ni = 0; ni < 4; ++ni) {
        const int cg = w * 64 + ni * 16 + lc;
#pragma unroll
        for (int r = 0; r < 4; ++r)
          O[(mi * 16 + quad * 4 + r) * 256 + cg] = acc[mi][ni][r];
      }
  } else {
#pragma unroll
    for (int mi = 0; mi < 4; ++mi)
#pragma unroll
      for (int ni = 0; ni < 4; ++ni) {
        const int cg = w * 64 + ni * 16 + lc;
        const float bi = bias[cg];
#pragma unroll
        for (int r = 0; r < 4; ++r) {
          const int rl = mi * 16 + quad * 4 + r;
          const float res = bf2f(residb[(bb * 64 + rl) * 256 + cg]);
          out[(bb * 64 + rl) * 256 + cg] = acc[mi][ni][r] + bi + res;
        }
      }
  }
}

// ---------------- fused split-K reduce + bias + value-resid + LN1 -> bf16 ----------------
__global__ __launch_bounds__(256) void reduce_ln_kernel(
    const float* __restrict__ part, const float* __restrict__ bias,
    const float* __restrict__ value, const float* __restrict__ gam,
    const float* __restrict__ bet, u16* __restrict__ dstb)
{
  const int t = threadIdx.x, w = t >> 6, lane = t & 63;
  const int row = blockIdx.x * 4 + w;
  const int e = row * 256 + lane * 4;
  const int col = lane * 4;
  const int bb = row >> 7, rl = row & 127, b = bb / 15, n = bb % 15;
  f32x4 s = *(const f32x4*)(part + e);
#pragma unroll
  for (int p = 1; p < 4; ++p) {
    const f32x4 v = *(const f32x4*)(part + p * 3932160 + e);
#pragma unroll
    for (int i = 0; i < 4; ++i) s[i] += v[i];
  }
  const f32x4 bi = *(const f32x4*)(bias + col);
  const f32x4 rv = *(const f32x4*)(value + (b * 1024 + n * 64 + rl) * 256 + col);
#pragma unroll
  for (int i = 0; i < 4; ++i) s[i] += bi[i] + rv[i];
  float sum = s[0] + s[1] + s[2] + s[3];
  float sq = s[0] * s[0] + s[1] * s[1] + s[2] * s[2] + s[3] * s[3];
#pragma unroll
  for (int m = 1; m < 64; m <<= 1) { sum += __shfl_xor(sum, m); sq += __shfl_xor(sq, m); }
  const float mean = sum * (1.0f / 256.0f);
  const float rs = rsqrtf(sq * (1.0f / 256.0f) - mean * mean + 1e-5f);
  const f32x4 g4 = *(const f32x4*)(gam + col);
  const f32x4 b4 = *(const f32x4*)(bet + col);
  u16x4 ob;
#pragma unroll
  for (int i = 0; i < 4; ++i) ob[i] = f2bf((s[i] - mean) * rs * g4[i] + b4[i]);
  *(u16x4*)(dstb + row * 256 + lane * 4) = ob;
}

// ---------------- layernorm (one wave per 256-wide row) ----------------
__global__ __launch_bounds__(256) void ln_kernel(
    const float* __restrict__ src, const float* __restrict__ gam, const float* __restrict__ bet,
    u16* __restrict__ dstb, float* __restrict__ dstf, int mode)
{
  const int t = threadIdx.x, w = t >> 6, lane = t & 63;
  const int row = blockIdx.x * 4 + w;
  const f32x4 v = *(const f32x4*)(src + row * 256 + lane * 4);
  float sum = v[0] + v[1] + v[2] + v[3];
  float sq = v[0] * v[0] + v[1] * v[1] + v[2] * v[2] + v[3] * v[3];
#pragma unroll
  for (int m = 1; m < 64; m <<= 1) { sum += __shfl_xor(sum, m); sq += __shfl_xor(sq, m); }
  const float mean = sum * (1.0f / 256.0f);
  const float rs = rsqrtf(sq * (1.0f / 256.0f) - mean * mean + 1e-5f);
  const f32x4 g4 = *(const f32x4*)(gam + lane * 4);
  const f32x4 b4 = *(const f32x4*)(bet + lane * 4);
  f32x4 o;
#pragma unroll
  for (int i = 0; i < 4; ++i)
    o[i] = (v[i] - mean) * rs * g4[i] + b4[i];
  if (mode == 0) {
    u16x4 ob;
#pragma unroll
    for (int i = 0; i < 4; ++i) ob[i] = f2bf(o[i]);
    *(u16x4*)(dstb + row * 256 + lane * 4) = ob;
  } else {
    const int bbq = row >> 7, r = row & 127, b = bbq / 15, n = bbq % 15;
    const bool valid = (n == 0) ? (r < 96) : ((n == 14) ? (r >= 32) : (r >= 32 && r < 96));
    if (valid)
      *(f32x4*)(dstf + ((b << 10) + n * 64 + r) * 256 + lane * 4) = o;
  }
}

extern "C" void kernel_launch(void* const* d_in, const int* in_sizes, int n_in,
                              void* d_out, int out_size, void* d_ws, size_t ws_size,
                              hipStream_t stream) {
  (void)in_sizes; (void)n_in; (void)out_size; (void)ws_size;
  const float* query = (const float*)d_in[0];
  const float* key   = (const float*)d_in[1];
  const float* value = (const float*)d_in[2];
  const float* Wq  = (const float*)d_in[3];
  const float* bq  = (const float*)d_in[4];
  const float* Wk  = (const float*)d_in[5];
  const float* bk  = (const float*)d_in[6];
  const float* Wv  = (const float*)d_in[7];
  const float* bv  = (const float*)d_in[8];
  const float* Wo  = (const float*)d_in[9];
  const float* bo  = (const float*)d_in[10];
  const float* g1  = (const float*)d_in[11];
  const float* b1  = (const float*)d_in[12];
  const float* Wff = (const float*)d_in[13];
  const float* bff = (const float*)d_in[14];
  const float* g2  = (const float*)d_in[15];
  const float* b2  = (const float*)d_in[16];

  // Ungathered-projection layout; peak 180,486,144 B:
  u16* ws  = (u16*)d_ws;
  u16* WT  = ws;                      // [0, 2162688)
  u16* qb  = ws + 2162688;            // 2,097,152 each (8192x256 bf16)
  u16* kb  = ws + 4259840;
  u16* vb  = ws + 6356992;
  u16* Pq  = ws + 8454144;            // 16,777,216 each (8192x2048 bf16)
  u16* Pk  = ws + 25231360;
  u16* VT  = ws + 42008576;           // 512 groups x [d=256][q'=128]
  u16* Obuf = ws + 58785792;          // 31,457,280 (gathered 15360x2048)
  u16* Pv  = Obuf;                    // first 16,777,216 of Obuf (dead before attn writes O)
  float* part = (float*)(ws + 8454144);   // 15,728,640 f32 over Pq+Pk (dead after attn)
  u16* xbuf   = ws + 49872896;            // 3,932,160 u16, within VT region (dead after attn)
  float* tmp2 = (float*)(ws + 58785792);  // over Obuf (dead after Wo gemm)

  convert_kernel<<<dim3(2048, 3), 256, 0, stream>>>(query, key, value, qb, kb, vb);
  transpose_kernel<<<dim3(2048, 5), 256, 0, stream>>>(Wq, Wk, Wv, Wo, Wff, WT);
  // Single proj pass over q/k/v on the original 8192 rows (R2 structure).
  proj_kernel<<<dim3(16, 64, 3), 256, 0, stream>>>(qb, kb, vb, WT, bq, bk, bv, Pq, Pk, Pv);
  vtrans_kernel<<<dim3(8, 512), 256, 0, stream>>>(Pv, VT);
  attn_kernel<<<dim3(8, 120), 512, 0, stream>>>(Pq, Pk, VT, Obuf);
  // Wo GEMM: 64x256 tiles, split-K=4 -> partials; fused reduce+LN1 consumes them.
  gemm64_kernel<<<dim3(240, 1, 4), 256, 0, stream>>>(Obuf, WT + 1572864, nullptr, nullptr, part, 2048, 2048, 0);
  reduce_ln_kernel<<<3840, 256, 0, stream>>>(part, bo, value, g1, b1, xbuf);
  // FF GEMM: 64x256 tiles, fused bias + residual epilogue.
  gemm64_kernel<<<dim3(240, 1, 1), 256, 0, stream>>>(xbuf, WT + 2097152, bff, xbuf, tmp2, 256, 256, 1);
  ln_kernel<<<3840, 256, 0, stream>>>(tmp2, g2, b2, nullptr, (float*)d_out, 1);
}

// Round 6
// 281.128 us; speedup vs baseline: 1.2136x; 1.1265x over previous
//
#include <hip/hip_runtime.h>
#include <cstdint>

typedef unsigned short u16;
typedef __attribute__((ext_vector_type(8))) short bf16x8;
typedef __attribute__((ext_vector_type(4))) float f32x4;
typedef __attribute__((ext_vector_type(4))) unsigned short u16x4;

#define AS_G __attribute__((address_space(1)))
#define AS_L __attribute__((address_space(3)))

__device__ __forceinline__ void gl_lds16(const u16* g, u16* l) {
  // async global->LDS, 16B/lane; LDS dest = wave-uniform base + lane*16
  __builtin_amdgcn_global_load_lds((const AS_G unsigned int*)g, (AS_L unsigned int*)l, 16, 0, 0);
}
__device__ __forceinline__ float bf2f(u16 u) {
  union { unsigned int i; float f; } v; v.i = ((unsigned int)u) << 16; return v.f;
}
__device__ __forceinline__ u16 f2bf(float f) {
  union { float f; unsigned int i; } v; v.f = f;
  unsigned int x = v.i;
  return (u16)((x + 0x7fffu + ((x >> 16) & 1u)) >> 16);  // RNE
}

// ---------------- fp32 -> bf16 convert of q/k/v ----------------
__global__ __launch_bounds__(256) void convert_kernel(
    const float* __restrict__ q, const float* __restrict__ k, const float* __restrict__ v,
    u16* __restrict__ qb, u16* __restrict__ kb, u16* __restrict__ vb)
{
  const int id = blockIdx.y;
  const float* s = (id == 0) ? q : (id == 1) ? k : v;
  u16* d = (id == 0) ? qb : (id == 1) ? kb : vb;
  const int o = (blockIdx.x * 256 + threadIdx.x) * 4;
  const f32x4 x = *(const f32x4*)(s + o);
  u16x4 y;
#pragma unroll
  for (int i = 0; i < 4; ++i) y[i] = f2bf(x[i]);
  *(u16x4*)(d + o) = y;
}

// ---------------- weight pre-transpose (fp32 src -> bf16 dst) ----------------
__global__ __launch_bounds__(256) void transpose_kernel(
    const float* __restrict__ s0, const float* __restrict__ s1, const float* __restrict__ s2,
    const float* __restrict__ s3, const float* __restrict__ s4, u16* __restrict__ wdst)
{
  const int id = blockIdx.y;
  const float* src; u16* dst; int rb, total;
  switch (id) {
    case 0:  src = s0; dst = wdst;           rb = 8;  total = 524288; break;
    case 1:  src = s1; dst = wdst + 524288;  rb = 8;  total = 524288; break;
    case 2:  src = s2; dst = wdst + 1048576; rb = 8;  total = 524288; break;
    case 3:  src = s3; dst = wdst + 1572864; rb = 11; total = 524288; break;
    default: src = s4; dst = wdst + 2097152; rb = 8;  total = 65536;  break;
  }
  const int o = blockIdx.x * 256 + threadIdx.x;
  if (o >= total) return;
  const int C_ = total >> rb;
  const int c = o >> rb, r = o & ((1 << rb) - 1);
  dst[o] = f2bf(src[r * C_ + c]);
}

// ---------------- QKV projection on the UNGATHERED 8192 rows ----------------
// R2 structure (best measured: 64.6 us).
__global__ __launch_bounds__(256) void proj_kernel(
    const u16* __restrict__ qb, const u16* __restrict__ kb, const u16* __restrict__ vb,
    const u16* __restrict__ wts, const float* __restrict__ bq, const float* __restrict__ bk,
    const float* __restrict__ bv, u16* __restrict__ Pq, u16* __restrict__ Pk,
    u16* __restrict__ Pv)
{
  __shared__ u16 lds[16384];            // buf b at [b*8192): A [0,4096)+B [4096,8192); epilogue: 64x136 per half
  const int t = threadIdx.x;
  const int w = t >> 6, lane = t & 63, quad = lane >> 4, lc = lane & 15;
  const int wy = w >> 1, wx = w & 1;
  // swizzle: same-by blocks (sharing the A slab) are XCD-local.
  const int flat = blockIdx.x + (blockIdx.y << 4);   // 0..1023
  const int tn = flat >> 6, by = flat & 63, z = blockIdx.z;
  const u16* A0 = ((z == 0) ? qb : (z == 1) ? kb : vb) + by * 32768;   // 128 rows x 256
  const u16* BT = wts + z * 524288 + tn * 128 * 256;

  const f32x4 fz = {0.f, 0.f, 0.f, 0.f};
  f32x4 acc[4][4];
#pragma unroll
  for (int i = 0; i < 4; ++i)
#pragma unroll
    for (int j = 0; j < 4; ++j) acc[i][j] = fz;

#define PROJ_STAGE(ck, b) do {                                         \
    const int ko_ = (ck) * 32 + w * 8;                                 \
    u16* Lb_ = &lds[(b) * 8192];                                       \
    gl_lds16(A0 + lane * 256 + ko_,        Lb_ + w * 1024);            \
    gl_lds16(A0 + (64 + lane) * 256 + ko_, Lb_ + w * 1024 + 512);      \
    gl_lds16(BT + lane * 256 + ko_,        Lb_ + 4096 + w * 1024);     \
    gl_lds16(BT + (64 + lane) * 256 + ko_, Lb_ + 4096 + w * 1024 + 512); \
  } while (0)

  PROJ_STAGE(0, 0);
#pragma unroll
  for (int ck = 0; ck < 8; ++ck) {
    const int cur = ck & 1;
    if (ck < 7) {
      PROJ_STAGE(ck + 1, cur ^ 1);
      asm volatile("s_waitcnt vmcnt(4)" ::: "memory");   // own chunk-ck loads landed; prefetch stays in flight
    } else {
      asm volatile("s_waitcnt vmcnt(0)" ::: "memory");
    }
    __builtin_amdgcn_s_barrier();                        // all waves' chunk-ck loads landed
    asm volatile("" ::: "memory");
    const u16* Ab = &lds[cur * 8192];
    const u16* Bb = &lds[cur * 8192 + 4096];
    bf16x8 af[4], bfg[4];
#pragma unroll
    for (int mi = 0; mi < 4; ++mi)
      af[mi] = *(const bf16x8*)&Ab[quad * 1024 + (wy * 64 + mi * 16 + lc) * 8];
#pragma unroll
    for (int ni = 0; ni < 4; ++ni)
      bfg[ni] = *(const bf16x8*)&Bb[quad * 1024 + (wx * 64 + ni * 16 + lc) * 8];
#pragma unroll
    for (int mi = 0; mi < 4; ++mi)
#pragma unroll
      for (int ni = 0; ni < 4; ++ni)
        acc[mi][ni] = __builtin_amdgcn_mfma_f32_16x16x32_bf16(af[mi], bfg[ni], acc[mi][ni], 0, 0, 0);
    asm volatile("s_waitcnt lgkmcnt(0)" ::: "memory");   // all ds_reads of buf[cur] done
    __builtin_amdgcn_s_barrier();                        // safe to overwrite buf[cur] next iter
  }
#undef PROJ_STAGE

  const float* bias = (z == 0) ? bq : (z == 1) ? bk : bv;
  u16* P = ((z == 0) ? Pq : (z == 1) ? Pk : Pv) + by * 262144;

  // Two 64-row epilogue passes; each uses only 64x136 u16 = 17408 B of LDS.
#pragma unroll
  for (int half = 0; half < 2; ++half) {
    __syncthreads();                     // prev pass reads / K-loop staging done
    if (wy == half) {
#pragma unroll
      for (int mi = 0; mi < 4; ++mi)
#pragma unroll
        for (int ni = 0; ni < 4; ++ni) {
          const int col = wx * 64 + ni * 16 + lc;
          const float bi = bias[tn * 128 + col];
#pragma unroll
          for (int r = 0; r < 4; ++r) {
            const int row = mi * 16 + quad * 4 + r;
            lds[row * 136 + col] = f2bf(acc[mi][ni][r] + bi);
          }
        }
    }
    __syncthreads();
#pragma unroll
    for (int p = 0; p < 4; ++p) {        // 256B-contiguous row segments, 16B/lane
      const int e = p * 2048 + t * 8;
      const int row = e >> 7, col0 = e & 127;
      *(bf16x8*)(P + (half * 64 + row) * 2048 + tn * 128 + col0) =
          *(const bf16x8*)&lds[row * 136 + col0];
    }
  }
}

// ---------------- Pv group-slab transpose (coalesced both sides) ----------------
__global__ __launch_bounds__(256) void vtrans_kernel(
    const u16* __restrict__ Pv, u16* __restrict__ VT)
{
  __shared__ u16 lT[4096];
  const int t = threadIdx.x;
  const int tile = blockIdx.x;          // 0..7
  const int g = blockIdx.y;             // 0..511
  const int q0 = (tile & 1) * 64, d0 = (tile >> 1) * 64;
  const u16* src = Pv + g * 32768;      // [q'=128][d=256]
  u16* dst = VT + g * 32768;            // [d=256][q'=128]
#pragma unroll
  for (int it = 0; it < 2; ++it) {
    const int e = it * 2048 + t * 8;
    const int lq = e >> 6, ld0 = e & 63;
    const bf16x8 v = *(const bf16x8*)(src + (q0 + lq) * 256 + d0 + ld0);
    const int kb = ((ld0 >> 3) + lq + (lq >> 3)) & 7;
    *(bf16x8*)&lT[lq * 64 + kb * 8] = v;
  }
  __syncthreads();
#pragma unroll
  for (int it = 0; it < 2; ++it) {
    const int e = it * 2048 + t * 8;
    const int ld = e >> 6, lq0 = e & 63;
    bf16x8 v;
#pragma unroll
    for (int i = 0; i < 8; ++i) {
      const int lq = lq0 + i;
      const int kb = ((ld >> 3) + lq + (lq >> 3)) & 7;
      v[i] = (short)lT[lq * 64 + kb * 8 + (ld & 7)];
    }
    *(bf16x8*)(dst + (d0 + ld) * 128 + q0 + lq0) = v;
  }
}

// ---------------- attention per (block, head) ----------------
__global__ __launch_bounds__(512) void attn_kernel(
    const u16* __restrict__ Pq, const u16* __restrict__ Pk,
    const u16* __restrict__ VT, u16* __restrict__ Obuf)
{
  __shared__ u16 lKV[16384];
  __shared__ u16 lP[16384];
  const int t = threadIdx.x;
  const int w = t >> 6, lane = t & 63, quad = lane >> 4, lc = lane & 15;
  const int h = blockIdx.x, bb = blockIdx.y;
  const int b = bb / 15, n = bb % 15;
  const int m0 = w * 16;
  const int r0 = b * 1024 + n * 64 + h * 16;
  const u16* Qb = Pq + r0 * 2048;
  const u16* Kb = Pk + r0 * 2048;
  const u16* Vb = VT + (b * 64 + n * 4 + h) * 32768;
  const f32x4 fz = {0.f, 0.f, 0.f, 0.f};

  bf16x8 aq[8];
#pragma unroll
  for (int kc = 0; kc < 8; ++kc)
    aq[kc] = *(const bf16x8*)(Qb + (m0 + lc) * 256 + kc * 32 + quad * 8);

  f32x4 s[8];
  for (int hk = 0; hk < 2; ++hk) {
    __syncthreads();
#pragma unroll
    for (int jj = 0; jj < 4; ++jj)
      gl_lds16(Kb + (hk * 64 + lane) * 256 + w * 32 + jj * 8, &lKV[w * 2048 + jj * 512]);
    __syncthreads();
#pragma unroll
    for (int ntl = 0; ntl < 4; ++ntl) {
      const int nt = hk * 4 + ntl;
      s[nt] = fz;
#pragma unroll
      for (int kc = 0; kc < 8; ++kc) {
        const bf16x8 bfr = *(const bf16x8*)&lKV[kc * 2048 + quad * 512 + (ntl * 16 + lc) * 8];
        s[nt] = __builtin_amdgcn_mfma_f32_16x16x32_bf16(aq[kc], bfr, s[nt], 0, 0, 0);
      }
    }
  }

  const float scale = 0.0625f;
#pragma unroll
  for (int r = 0; r < 4; ++r) {
    float mx = -3.0e38f;
#pragma unroll
    for (int nt = 0; nt < 8; ++nt) mx = fmaxf(mx, s[nt][r]);
    mx = fmaxf(mx, __shfl_xor(mx, 1)); mx = fmaxf(mx, __shfl_xor(mx, 2));
    mx = fmaxf(mx, __shfl_xor(mx, 4)); mx = fmaxf(mx, __shfl_xor(mx, 8));
    mx *= scale;
    float sm = 0.0f;
#pragma unroll
    for (int nt = 0; nt < 8; ++nt) {
      const float e = __expf(s[nt][r] * scale - mx);
      s[nt][r] = e; sm += e;
    }
    sm += __shfl_xor(sm, 1); sm += __shfl_xor(sm, 2);
    sm += __shfl_xor(sm, 4); sm += __shfl_xor(sm, 8);
    const float inv = 1.0f / sm;
    const int q = m0 + quad * 4 + r;
#pragma unroll
    for (int nt = 0; nt < 8; ++nt) {
      const int k = nt * 16 + lc;
      lP[(k >> 5) * 4096 + ((k >> 3) & 3) * 1024 + q * 8 + (k & 7)] = f2bf(s[nt][r] * inv);
    }
  }
  __syncthreads();

  bf16x8 ap[4];
#pragma unroll
  for (int kc2 = 0; kc2 < 4; ++kc2)
    ap[kc2] = *(const bf16x8*)&lP[kc2 * 4096 + quad * 1024 + (m0 + lc) * 8];

  f32x4 o[16];
#pragma unroll
  for (int nt = 0; nt < 16; ++nt) o[nt] = fz;

  for (int hk = 0; hk < 2; ++hk) {
    if (hk) __syncthreads();
#pragma unroll
    for (int jj = 0; jj < 4; ++jj) {
      const int i = w * 4 + jj;
      const int kc2l = i >> 4, cb = (i >> 2) & 3, db = (i & 3) * 64;
      gl_lds16(Vb + (db + lane) * 128 + (hk * 2 + kc2l) * 32 + cb * 8,
               &lKV[kc2l * 8192 + cb * 2048 + db * 8]);
    }
    __syncthreads();
#pragma unroll
    for (int nt = 0; nt < 16; ++nt)
#pragma unroll
      for (int kc2l = 0; kc2l < 2; ++kc2l) {
        const bf16x8 bfr = *(const bf16x8*)&lKV[kc2l * 8192 + quad * 2048 + (nt * 16 + lc) * 8];
        o[nt] = __builtin_amdgcn_mfma_f32_16x16x32_bf16(ap[hk * 2 + kc2l], bfr, o[nt], 0, 0, 0);
      }
  }

  u16* Ob = Obuf + bb * 262144 + h * 32768;   // gathered output (separate buffer)
#pragma unroll
  for (int nt = 0; nt < 16; ++nt)
#pragma unroll
    for (int r = 0; r < 4; ++r) {
      const int q = m0 + quad * 4 + r;
      Ob[q * 256 + nt * 16 + lc] = f2bf(o[nt][r]);
    }
}

// ---------------- Wo GEMM over SURVIVING rows only (M=8192), split-K=4 ----------------
// NEW (this round): the reference slices away 47% of the gathered rows AFTER
// the row-local Wo/LN1/FF/LN2 chain, so the slice commutes backward: output
// row j in [0,1024) maps to window n=clamp((j-32)/64,0,14), wr=j-64n; Obuf
// source row = (b*15+n)*128+wr. Gather applied via per-lane gl_lds16 source
// addresses (free). 64x256 tile, counted-vmcnt(5) double-buffered staging.
__global__ __launch_bounds__(256) void gemm_wo_kernel(
    const u16* __restrict__ A, const u16* __restrict__ BT, float* __restrict__ out)
{
  __shared__ u16 lA[2][2048];           // [ks=4][64 rows][8]
  __shared__ u16 lB[2][8192];           // [ks=4][256 rows][8]
  const int t = threadIdx.x;
  const int w = t >> 6, lane = t & 63, quad = lane >> 4, lc = lane & 15;
  const int bb = blockIdx.x, kz = blockIdx.z;
  const int k0 = kz * 512;              // kslice = 2048/4
  // per-lane gathered A row (row = bb*64 + lane of the surviving-row matrix)
  const int g = bb * 64 + lane;
  const int b_ = g >> 10, j = g & 1023;
  int n = (j - 32) >> 6; n = (n < 0) ? 0 : ((n > 14) ? 14 : n);
  const int wr = j - (n << 6);
  const u16* Arow = A + (((b_ * 15 + n) << 7) + wr) * 2048 + k0;
  const u16* BT0 = BT + k0;

  const f32x4 fz = {0.f, 0.f, 0.f, 0.f};
  f32x4 acc[4][4];
#pragma unroll
  for (int i = 0; i < 4; ++i)
#pragma unroll
    for (int jj = 0; jj < 4; ++jj) acc[i][jj] = fz;

#define GWO_STAGE(ck, b) do {                                          \
    const int ko_ = (ck) * 32 + w * 8;                                 \
    gl_lds16(Arow + ko_, &lA[b][w * 512]);                             \
    _Pragma("unroll")                                                  \
    for (int sg_ = 0; sg_ < 4; ++sg_)                                  \
      gl_lds16(BT0 + (sg_ * 64 + lane) * 2048 + ko_,                   \
               &lB[b][w * 2048 + sg_ * 512]);                          \
  } while (0)

  GWO_STAGE(0, 0);
  for (int ck = 0; ck < 16; ++ck) {
    const int cur = ck & 1;
    if (ck < 15) {
      GWO_STAGE(ck + 1, cur ^ 1);
      asm volatile("s_waitcnt vmcnt(5)" ::: "memory");
    } else {
      asm volatile("s_waitcnt vmcnt(0)" ::: "memory");
    }
    __builtin_amdgcn_s_barrier();
    asm volatile("" ::: "memory");
    bf16x8 af[4], bfg[4];
#pragma unroll
    for (int mi = 0; mi < 4; ++mi)
      af[mi] = *(const bf16x8*)&lA[cur][quad * 512 + (mi * 16 + lc) * 8];
#pragma unroll
    for (int ni = 0; ni < 4; ++ni) {
      const int cl = w * 64 + ni * 16 + lc;
      bfg[ni] = *(const bf16x8*)&lB[cur][quad * 2048 + cl * 8];
    }
#pragma unroll
    for (int mi = 0; mi < 4; ++mi)
#pragma unroll
      for (int ni = 0; ni < 4; ++ni)
        acc[mi][ni] = __builtin_amdgcn_mfma_f32_16x16x32_bf16(af[mi], bfg[ni], acc[mi][ni], 0, 0, 0);
    asm volatile("s_waitcnt lgkmcnt(0)" ::: "memory");
    __builtin_amdgcn_s_barrier();
  }
#undef GWO_STAGE

  float* O = out + kz * 2097152 + bb * 64 * 256;
#pragma unroll
  for (int mi = 0; mi < 4; ++mi)
#pragma unroll
    for (int ni = 0; ni < 4; ++ni) {
      const int cg = w * 64 + ni * 16 + lc;
#pragma unroll
      for (int r = 0; r < 4; ++r)
        O[(mi * 16 + quad * 4 + r) * 256 + cg] = acc[mi][ni][r];
    }
}

// ---------------- FF GEMM (64x128 tile, K=256, fused bias+resid epilogue) ----------------
// R2-proven shape; M=8192 now; grid (2 tn, 128 bb) = 256 blocks for TLP.
__global__ __launch_bounds__(256) void gemm_ff_kernel(
    const u16* __restrict__ A, const u16* __restrict__ BT, const float* __restrict__ bias,
    const u16* __restrict__ residb, float* __restrict__ out)
{
  __shared__ u16 lA[2][2048];
  __shared__ u16 lB[2][4096];
  const int t = threadIdx.x;
  const int w = t >> 6, lane = t & 63, quad = lane >> 4, lc = lane & 15;
  const int tn = blockIdx.x, bb = blockIdx.y;
  const u16* A0 = A + bb * 64 * 256;
  const u16* BT0 = BT + tn * 128 * 256;

  const f32x4 fz = {0.f, 0.f, 0.f, 0.f};
  f32x4 acc[4][2];
#pragma unroll
  for (int i = 0; i < 4; ++i) { acc[i][0] = fz; acc[i][1] = fz; }

#define GFF_STAGE(ck, b) do {                                          \
    const int ko_ = (ck) * 32 + w * 8;                                 \
    gl_lds16(A0 + lane * 256 + ko_,        &lA[b][w * 512]);           \
    gl_lds16(BT0 + lane * 256 + ko_,       &lB[b][w * 1024]);          \
    gl_lds16(BT0 + (64 + lane) * 256 + ko_, &lB[b][w * 1024 + 512]);   \
  } while (0)

  GFF_STAGE(0, 0);
  for (int ck = 0; ck < 8; ++ck) {
    const int cur = ck & 1;
    if (ck < 7) {
      GFF_STAGE(ck + 1, cur ^ 1);
      asm volatile("s_waitcnt vmcnt(3)" ::: "memory");
    } else {
      asm volatile("s_waitcnt vmcnt(0)" ::: "memory");
    }
    __builtin_amdgcn_s_barrier();
    asm volatile("" ::: "memory");
    bf16x8 af[4], bfg[2];
#pragma unroll
    for (int mi = 0; mi < 4; ++mi)
      af[mi] = *(const bf16x8*)&lA[cur][quad * 512 + (mi * 16 + lc) * 8];
#pragma unroll
    for (int ni = 0; ni < 2; ++ni) {
      const int cl = w * 32 + ni * 16 + lc;
      bfg[ni] = *(const bf16x8*)&lB[cur][quad * 1024 + (cl >> 6) * 512 + (cl & 63) * 8];
    }
#pragma unroll
    for (int mi = 0; mi < 4; ++mi)
#pragma unroll
      for (int ni = 0; ni < 2; ++ni)
        acc[mi][ni] = __builtin_amdgcn_mfma_f32_16x16x32_bf16(af[mi], bfg[ni], acc[mi][ni], 0, 0, 0);
    asm volatile("s_waitcnt lgkmcnt(0)" ::: "memory");
    __builtin_amdgcn_s_barrier();
  }
#undef GFF_STAGE

#pragma unroll
  for (int mi = 0; mi < 4; ++mi)
#pragma unroll
    for (int ni = 0; ni < 2; ++ni) {
      const int cg = tn * 128 + w * 32 + ni * 16 + lc;
      const float bi = bias[cg];
#pragma unroll
      for (int r = 0; r < 4; ++r) {
        const int rl = mi * 16 + quad * 4 + r;
        const float res = bf2f(residb[(bb * 64 + rl) * 256 + cg]);
        out[(bb * 64 + rl) * 256 + cg] = acc[mi][ni][r] + bi + res;
      }
    }
}

// ---------------- fused split-K reduce + bias + value-resid + LN1 -> bf16 ----------------
// M=8192 rows; value residual is now LINEAR: source row == output row.
__global__ __launch_bounds__(256) void reduce_ln_kernel(
    const float* __restrict__ part, const float* __restrict__ bias,
    const float* __restrict__ value, const float* __restrict__ gam,
    const float* __restrict__ bet, u16* __restrict__ dstb)
{
  const int t = threadIdx.x, w = t >> 6, lane = t & 63;
  const int row = blockIdx.x * 4 + w;
  const int e = row * 256 + lane * 4;
  const int col = lane * 4;
  f32x4 s = *(const f32x4*)(part + e);
#pragma unroll
  for (int p = 1; p < 4; ++p) {
    const f32x4 v = *(const f32x4*)(part + p * 2097152 + e);
#pragma unroll
    for (int i = 0; i < 4; ++i) s[i] += v[i];
  }
  const f32x4 bi = *(const f32x4*)(bias + col);
  const f32x4 rv = *(const f32x4*)(value + e);
#pragma unroll
  for (int i = 0; i < 4; ++i) s[i] += bi[i] + rv[i];
  float sum = s[0] + s[1] + s[2] + s[3];
  float sq = s[0] * s[0] + s[1] * s[1] + s[2] * s[2] + s[3] * s[3];
#pragma unroll
  for (int m = 1; m < 64; m <<= 1) { sum += __shfl_xor(sum, m); sq += __shfl_xor(sq, m); }
  const float mean = sum * (1.0f / 256.0f);
  const float rs = rsqrtf(sq * (1.0f / 256.0f) - mean * mean + 1e-5f);
  const f32x4 g4 = *(const f32x4*)(gam + col);
  const f32x4 b4 = *(const f32x4*)(bet + col);
  u16x4 ob;
#pragma unroll
  for (int i = 0; i < 4; ++i) ob[i] = f2bf((s[i] - mean) * rs * g4[i] + b4[i]);
  *(u16x4*)(dstb + row * 256 + lane * 4) = ob;
}

// ---------------- final layernorm -> d_out (all 8192 rows valid now) ----------------
__global__ __launch_bounds__(256) void ln2_kernel(
    const float* __restrict__ src, const float* __restrict__ gam, const float* __restrict__ bet,
    float* __restrict__ dstf)
{
  const int t = threadIdx.x, w = t >> 6, lane = t & 63;
  const int row = blockIdx.x * 4 + w;
  const f32x4 v = *(const f32x4*)(src + row * 256 + lane * 4);
  float sum = v[0] + v[1] + v[2] + v[3];
  float sq = v[0] * v[0] + v[1] * v[1] + v[2] * v[2] + v[3] * v[3];
#pragma unroll
  for (int m = 1; m < 64; m <<= 1) { sum += __shfl_xor(sum, m); sq += __shfl_xor(sq, m); }
  const float mean = sum * (1.0f / 256.0f);
  const float rs = rsqrtf(sq * (1.0f / 256.0f) - mean * mean + 1e-5f);
  const f32x4 g4 = *(const f32x4*)(gam + lane * 4);
  const f32x4 b4 = *(const f32x4*)(bet + lane * 4);
  f32x4 o;
#pragma unroll
  for (int i = 0; i < 4; ++i)
    o[i] = (v[i] - mean) * rs * g4[i] + b4[i];
  *(f32x4*)(dstf + row * 256 + lane * 4) = o;
}

extern "C" void kernel_launch(void* const* d_in, const int* in_sizes, int n_in,
                              void* d_out, int out_size, void* d_ws, size_t ws_size,
                              hipStream_t stream) {
  (void)in_sizes; (void)n_in; (void)out_size; (void)ws_size;
  const float* query = (const float*)d_in[0];
  const float* key   = (const float*)d_in[1];
  const float* value = (const float*)d_in[2];
  const float* Wq  = (const float*)d_in[3];
  const float* bq  = (const float*)d_in[4];
  const float* Wk  = (const float*)d_in[5];
  const float* bk  = (const float*)d_in[6];
  const float* Wv  = (const float*)d_in[7];
  const float* bv  = (const float*)d_in[8];
  const float* Wo  = (const float*)d_in[9];
  const float* bo  = (const float*)d_in[10];
  const float* g1  = (const float*)d_in[11];
  const float* b1  = (const float*)d_in[12];
  const float* Wff = (const float*)d_in[13];
  const float* bff = (const float*)d_in[14];
  const float* g2  = (const float*)d_in[15];
  const float* b2  = (const float*)d_in[16];

  u16* ws  = (u16*)d_ws;
  u16* WT  = ws;                      // [0, 2162688)
  u16* qb  = ws + 2162688;            // 2,097,152 each (8192x256 bf16)
  u16* kb  = ws + 4259840;
  u16* vb  = ws + 6356992;
  u16* Pq  = ws + 8454144;            // 16,777,216 each (8192x2048 bf16)
  u16* Pk  = ws + 25231360;
  u16* VT  = ws + 42008576;           // 512 groups x [d=256][q'=128]
  u16* Obuf = ws + 58785792;          // 31,457,280 (gathered 15360x2048)
  u16* Pv  = Obuf;                    // first 16,777,216 of Obuf (dead before attn writes O)
  float* part = (float*)(ws + 8454144);   // 4 x 2,097,152 f32 over Pq+Pk (dead after attn)
  u16* xbuf   = ws + 49872896;            // 2,097,152 u16 within VT region (dead after attn)
  float* tmp2 = (float*)(ws + 58785792);  // 2,097,152 f32 over Obuf (dead after Wo gemm)

  convert_kernel<<<dim3(2048, 3), 256, 0, stream>>>(query, key, value, qb, kb, vb);
  transpose_kernel<<<dim3(2048, 5), 256, 0, stream>>>(Wq, Wk, Wv, Wo, Wff, WT);
  proj_kernel<<<dim3(16, 64, 3), 256, 0, stream>>>(qb, kb, vb, WT, bq, bk, bv, Pq, Pk, Pv);
  vtrans_kernel<<<dim3(8, 512), 256, 0, stream>>>(Pv, VT);
  attn_kernel<<<dim3(8, 120), 512, 0, stream>>>(Pq, Pk, VT, Obuf);
  // Wo GEMM on surviving rows only (M=8192), split-K=4 -> partials.
  gemm_wo_kernel<<<dim3(128, 1, 4), 256, 0, stream>>>(Obuf, WT + 1572864, part);
  reduce_ln_kernel<<<2048, 256, 0, stream>>>(part, bo, value, g1, b1, xbuf);
  gemm_ff_kernel<<<dim3(2, 128), 256, 0, stream>>>(xbuf, WT + 2097152, bff, xbuf, tmp2);
  ln2_kernel<<<2048, 256, 0, stream>>>(tmp2, g2, b2, (float*)d_out);
}

// Round 7
// 256.512 us; speedup vs baseline: 1.3301x; 1.0960x over previous
//
#include <hip/hip_runtime.h>
#include <cstdint>

typedef unsigned short u16;
typedef __attribute__((ext_vector_type(8))) short bf16x8;
typedef __attribute__((ext_vector_type(4))) float f32x4;
typedef __attribute__((ext_vector_type(4))) unsigned short u16x4;

#define AS_G __attribute__((address_space(1)))
#define AS_L __attribute__((address_space(3)))

__device__ __forceinline__ void gl_lds16(const u16* g, u16* l) {
  // async global->LDS, 16B/lane; LDS dest = wave-uniform base + lane*16
  __builtin_amdgcn_global_load_lds((const AS_G unsigned int*)g, (AS_L unsigned int*)l, 16, 0, 0);
}
__device__ __forceinline__ float bf2f(u16 u) {
  union { unsigned int i; float f; } v; v.i = ((unsigned int)u) << 16; return v.f;
}
__device__ __forceinline__ u16 f2bf(float f) {
  union { float f; unsigned int i; } v; v.f = f;
  unsigned int x = v.i;
  return (u16)((x + 0x7fffu + ((x >> 16) & 1u)) >> 16);  // RNE
}

// ---------------- fp32 -> bf16 convert of q/k/v ----------------
__global__ __launch_bounds__(256) void convert_kernel(
    const float* __restrict__ q, const float* __restrict__ k, const float* __restrict__ v,
    u16* __restrict__ qb, u16* __restrict__ kb, u16* __restrict__ vb)
{
  const int id = blockIdx.y;
  const float* s = (id == 0) ? q : (id == 1) ? k : v;
  u16* d = (id == 0) ? qb : (id == 1) ? kb : vb;
  const int o = (blockIdx.x * 256 + threadIdx.x) * 4;
  const f32x4 x = *(const f32x4*)(s + o);
  u16x4 y;
#pragma unroll
  for (int i = 0; i < 4; ++i) y[i] = f2bf(x[i]);
  *(u16x4*)(d + o) = y;
}

// ---------------- weight pre-transpose (fp32 src -> bf16 dst) ----------------
__global__ __launch_bounds__(256) void transpose_kernel(
    const float* __restrict__ s0, const float* __restrict__ s1, const float* __restrict__ s2,
    const float* __restrict__ s3, const float* __restrict__ s4, u16* __restrict__ wdst)
{
  const int id = blockIdx.y;
  const float* src; u16* dst; int rb, total;
  switch (id) {
    case 0:  src = s0; dst = wdst;           rb = 8;  total = 524288; break;
    case 1:  src = s1; dst = wdst + 524288;  rb = 8;  total = 524288; break;
    case 2:  src = s2; dst = wdst + 1048576; rb = 8;  total = 524288; break;
    case 3:  src = s3; dst = wdst + 1572864; rb = 11; total = 524288; break;
    default: src = s4; dst = wdst + 2097152; rb = 8;  total = 65536;  break;
  }
  const int o = blockIdx.x * 256 + threadIdx.x;
  if (o >= total) return;
  const int C_ = total >> rb;
  const int c = o >> rb, r = o & ((1 << rb) - 1);
  dst[o] = f2bf(src[r * C_ + c]);
}

// ---------------- QKV projection on the UNGATHERED 8192 rows ----------------
// R2 structure (best measured: 64.6 us).
__global__ __launch_bounds__(256) void proj_kernel(
    const u16* __restrict__ qb, const u16* __restrict__ kb, const u16* __restrict__ vb,
    const u16* __restrict__ wts, const float* __restrict__ bq, const float* __restrict__ bk,
    const float* __restrict__ bv, u16* __restrict__ Pq, u16* __restrict__ Pk,
    u16* __restrict__ Pv)
{
  __shared__ u16 lds[16384];            // buf b at [b*8192): A [0,4096)+B [4096,8192); epilogue: 64x136 per half
  const int t = threadIdx.x;
  const int w = t >> 6, lane = t & 63, quad = lane >> 4, lc = lane & 15;
  const int wy = w >> 1, wx = w & 1;
  // swizzle: same-by blocks (sharing the A slab) are XCD-local.
  const int flat = blockIdx.x + (blockIdx.y << 4);   // 0..1023
  const int tn = flat >> 6, by = flat & 63, z = blockIdx.z;
  const u16* A0 = ((z == 0) ? qb : (z == 1) ? kb : vb) + by * 32768;   // 128 rows x 256
  const u16* BT = wts + z * 524288 + tn * 128 * 256;

  const f32x4 fz = {0.f, 0.f, 0.f, 0.f};
  f32x4 acc[4][4];
#pragma unroll
  for (int i = 0; i < 4; ++i)
#pragma unroll
    for (int j = 0; j < 4; ++j) acc[i][j] = fz;

#define PROJ_STAGE(ck, b) do {                                         \
    const int ko_ = (ck) * 32 + w * 8;                                 \
    u16* Lb_ = &lds[(b) * 8192];                                       \
    gl_lds16(A0 + lane * 256 + ko_,        Lb_ + w * 1024);            \
    gl_lds16(A0 + (64 + lane) * 256 + ko_, Lb_ + w * 1024 + 512);      \
    gl_lds16(BT + lane * 256 + ko_,        Lb_ + 4096 + w * 1024);     \
    gl_lds16(BT + (64 + lane) * 256 + ko_, Lb_ + 4096 + w * 1024 + 512); \
  } while (0)

  PROJ_STAGE(0, 0);
#pragma unroll
  for (int ck = 0; ck < 8; ++ck) {
    const int cur = ck & 1;
    if (ck < 7) {
      PROJ_STAGE(ck + 1, cur ^ 1);
      asm volatile("s_waitcnt vmcnt(4)" ::: "memory");   // own chunk-ck loads landed; prefetch stays in flight
    } else {
      asm volatile("s_waitcnt vmcnt(0)" ::: "memory");
    }
    __builtin_amdgcn_s_barrier();                        // all waves' chunk-ck loads landed
    asm volatile("" ::: "memory");
    const u16* Ab = &lds[cur * 8192];
    const u16* Bb = &lds[cur * 8192 + 4096];
    bf16x8 af[4], bfg[4];
#pragma unroll
    for (int mi = 0; mi < 4; ++mi)
      af[mi] = *(const bf16x8*)&Ab[quad * 1024 + (wy * 64 + mi * 16 + lc) * 8];
#pragma unroll
    for (int ni = 0; ni < 4; ++ni)
      bfg[ni] = *(const bf16x8*)&Bb[quad * 1024 + (wx * 64 + ni * 16 + lc) * 8];
#pragma unroll
    for (int mi = 0; mi < 4; ++mi)
#pragma unroll
      for (int ni = 0; ni < 4; ++ni)
        acc[mi][ni] = __builtin_amdgcn_mfma_f32_16x16x32_bf16(af[mi], bfg[ni], acc[mi][ni], 0, 0, 0);
    asm volatile("s_waitcnt lgkmcnt(0)" ::: "memory");   // all ds_reads of buf[cur] done
    __builtin_amdgcn_s_barrier();                        // safe to overwrite buf[cur] next iter
  }
#undef PROJ_STAGE

  const float* bias = (z == 0) ? bq : (z == 1) ? bk : bv;
  u16* P = ((z == 0) ? Pq : (z == 1) ? Pk : Pv) + by * 262144;

  // Two 64-row epilogue passes; each uses only 64x136 u16 = 17408 B of LDS.
#pragma unroll
  for (int half = 0; half < 2; ++half) {
    __syncthreads();                     // prev pass reads / K-loop staging done
    if (wy == half) {
#pragma unroll
      for (int mi = 0; mi < 4; ++mi)
#pragma unroll
        for (int ni = 0; ni < 4; ++ni) {
          const int col = wx * 64 + ni * 16 + lc;
          const float bi = bias[tn * 128 + col];
#pragma unroll
          for (int r = 0; r < 4; ++r) {
            const int row = mi * 16 + quad * 4 + r;
            lds[row * 136 + col] = f2bf(acc[mi][ni][r] + bi);
          }
        }
    }
    __syncthreads();
#pragma unroll
    for (int p = 0; p < 4; ++p) {        // 256B-contiguous row segments, 16B/lane
      const int e = p * 2048 + t * 8;
      const int row = e >> 7, col0 = e & 127;
      *(bf16x8*)(P + (half * 64 + row) * 2048 + tn * 128 + col0) =
          *(const bf16x8*)&lds[row * 136 + col0];
    }
  }
}

// ---------------- Pv group-slab transpose (coalesced both sides) ----------------
__global__ __launch_bounds__(256) void vtrans_kernel(
    const u16* __restrict__ Pv, u16* __restrict__ VT)
{
  __shared__ u16 lT[4096];
  const int t = threadIdx.x;
  const int tile = blockIdx.x;          // 0..7
  const int g = blockIdx.y;             // 0..511
  const int q0 = (tile & 1) * 64, d0 = (tile >> 1) * 64;
  const u16* src = Pv + g * 32768;      // [q'=128][d=256]
  u16* dst = VT + g * 32768;            // [d=256][q'=128]
#pragma unroll
  for (int it = 0; it < 2; ++it) {
    const int e = it * 2048 + t * 8;
    const int lq = e >> 6, ld0 = e & 63;
    const bf16x8 v = *(const bf16x8*)(src + (q0 + lq) * 256 + d0 + ld0);
    const int kb = ((ld0 >> 3) + lq + (lq >> 3)) & 7;
    *(bf16x8*)&lT[lq * 64 + kb * 8] = v;
  }
  __syncthreads();
#pragma unroll
  for (int it = 0; it < 2; ++it) {
    const int e = it * 2048 + t * 8;
    const int ld = e >> 6, lq0 = e & 63;
    bf16x8 v;
#pragma unroll
    for (int i = 0; i < 8; ++i) {
      const int lq = lq0 + i;
      const int kb = ((ld >> 3) + lq + (lq >> 3)) & 7;
      v[i] = (short)lT[lq * 64 + kb * 8 + (ld & 7)];
    }
    *(bf16x8*)(dst + (d0 + ld) * 128 + q0 + lq0) = v;
  }
}

// ---------------- attention per DISTINCT unit (dedup'd) ----------------
// NEW (this round): units (b,n,h) collapse on M = 4n+h — (n=0,h=4) and
// (n=1,h=0) read the SAME P rows r0 = b*1024+16M and the SAME VT group
// b*64+M, producing identical output; the reference's final slice keeps
// exactly one (n,h) copy per M (n=0: h<6, mid: 2<=h<6, n=14: h>=2 ->
// 6+13*4+6 = 64 = one per M). So grid is (M=64, b=8) = 512 blocks instead
// of 960, and the output base r0 makes Obuf a LINEAR gathered [8192][2048].
__global__ __launch_bounds__(512) void attn_kernel(
    const u16* __restrict__ Pq, const u16* __restrict__ Pk,
    const u16* __restrict__ VT, u16* __restrict__ Obuf)
{
  __shared__ u16 lKV[16384];
  __shared__ u16 lP[16384];
  const int t = threadIdx.x;
  const int w = t >> 6, lane = t & 63, quad = lane >> 4, lc = lane & 15;
  const int M = blockIdx.x, b = blockIdx.y;
  const int m0 = w * 16;
  const int r0 = b * 1024 + M * 16;
  const u16* Qb = Pq + r0 * 2048;
  const u16* Kb = Pk + r0 * 2048;
  const u16* Vb = VT + (b * 64 + M) * 32768;
  const f32x4 fz = {0.f, 0.f, 0.f, 0.f};

  bf16x8 aq[8];
#pragma unroll
  for (int kc = 0; kc < 8; ++kc)
    aq[kc] = *(const bf16x8*)(Qb + (m0 + lc) * 256 + kc * 32 + quad * 8);

  f32x4 s[8];
  for (int hk = 0; hk < 2; ++hk) {
    __syncthreads();
#pragma unroll
    for (int jj = 0; jj < 4; ++jj)
      gl_lds16(Kb + (hk * 64 + lane) * 256 + w * 32 + jj * 8, &lKV[w * 2048 + jj * 512]);
    __syncthreads();
#pragma unroll
    for (int ntl = 0; ntl < 4; ++ntl) {
      const int nt = hk * 4 + ntl;
      s[nt] = fz;
#pragma unroll
      for (int kc = 0; kc < 8; ++kc) {
        const bf16x8 bfr = *(const bf16x8*)&lKV[kc * 2048 + quad * 512 + (ntl * 16 + lc) * 8];
        s[nt] = __builtin_amdgcn_mfma_f32_16x16x32_bf16(aq[kc], bfr, s[nt], 0, 0, 0);
      }
    }
  }

  const float scale = 0.0625f;
#pragma unroll
  for (int r = 0; r < 4; ++r) {
    float mx = -3.0e38f;
#pragma unroll
    for (int nt = 0; nt < 8; ++nt) mx = fmaxf(mx, s[nt][r]);
    mx = fmaxf(mx, __shfl_xor(mx, 1)); mx = fmaxf(mx, __shfl_xor(mx, 2));
    mx = fmaxf(mx, __shfl_xor(mx, 4)); mx = fmaxf(mx, __shfl_xor(mx, 8));
    mx *= scale;
    float sm = 0.0f;
#pragma unroll
    for (int nt = 0; nt < 8; ++nt) {
      const float e = __expf(s[nt][r] * scale - mx);
      s[nt][r] = e; sm += e;
    }
    sm += __shfl_xor(sm, 1); sm += __shfl_xor(sm, 2);
    sm += __shfl_xor(sm, 4); sm += __shfl_xor(sm, 8);
    const float inv = 1.0f / sm;
    const int q = m0 + quad * 4 + r;
#pragma unroll
    for (int nt = 0; nt < 8; ++nt) {
      const int k = nt * 16 + lc;
      lP[(k >> 5) * 4096 + ((k >> 3) & 3) * 1024 + q * 8 + (k & 7)] = f2bf(s[nt][r] * inv);
    }
  }
  __syncthreads();

  bf16x8 ap[4];
#pragma unroll
  for (int kc2 = 0; kc2 < 4; ++kc2)
    ap[kc2] = *(const bf16x8*)&lP[kc2 * 4096 + quad * 1024 + (m0 + lc) * 8];

  f32x4 o[16];
#pragma unroll
  for (int nt = 0; nt < 16; ++nt) o[nt] = fz;

  for (int hk = 0; hk < 2; ++hk) {
    if (hk) __syncthreads();
#pragma unroll
    for (int jj = 0; jj < 4; ++jj) {
      const int i = w * 4 + jj;
      const int kc2l = i >> 4, cb = (i >> 2) & 3, db = (i & 3) * 64;
      gl_lds16(Vb + (db + lane) * 128 + (hk * 2 + kc2l) * 32 + cb * 8,
               &lKV[kc2l * 8192 + cb * 2048 + db * 8]);
    }
    __syncthreads();
#pragma unroll
    for (int nt = 0; nt < 16; ++nt)
#pragma unroll
      for (int kc2l = 0; kc2l < 2; ++kc2l) {
        const bf16x8 bfr = *(const bf16x8*)&lKV[kc2l * 8192 + quad * 2048 + (nt * 16 + lc) * 8];
        o[nt] = __builtin_amdgcn_mfma_f32_16x16x32_bf16(ap[hk * 2 + kc2l], bfr, o[nt], 0, 0, 0);
      }
  }

  u16* Ob = Obuf + r0 * 2048;           // linear gathered output rows [16M,16M+16)
#pragma unroll
  for (int nt = 0; nt < 16; ++nt)
#pragma unroll
    for (int r = 0; r < 4; ++r) {
      const int q = m0 + quad * 4 + r;
      Ob[q * 256 + nt * 16 + lc] = f2bf(o[nt][r]);
    }
}

// ---------------- Wo GEMM on the linear gathered rows (M=8192), split-K=4 ----------------
// A reads are now fully linear (gather happened at attn write time).
__global__ __launch_bounds__(256) void gemm_wo_kernel(
    const u16* __restrict__ A, const u16* __restrict__ BT, float* __restrict__ out)
{
  __shared__ u16 lA[2][2048];           // [ks=4][64 rows][8]
  __shared__ u16 lB[2][8192];           // [ks=4][256 rows][8]
  const int t = threadIdx.x;
  const int w = t >> 6, lane = t & 63, quad = lane >> 4, lc = lane & 15;
  const int bb = blockIdx.x, kz = blockIdx.z;
  const int k0 = kz * 512;              // kslice = 2048/4
  const u16* Arow = A + (bb * 64 + lane) * 2048 + k0;
  const u16* BT0 = BT + k0;

  const f32x4 fz = {0.f, 0.f, 0.f, 0.f};
  f32x4 acc[4][4];
#pragma unroll
  for (int i = 0; i < 4; ++i)
#pragma unroll
    for (int jj = 0; jj < 4; ++jj) acc[i][jj] = fz;

#define GWO_STAGE(ck, b) do {                                          \
    const int ko_ = (ck) * 32 + w * 8;                                 \
    gl_lds16(Arow + ko_, &lA[b][w * 512]);                             \
    _Pragma("unroll")                                                  \
    for (int sg_ = 0; sg_ < 4; ++sg_)                                  \
      gl_lds16(BT0 + (sg_ * 64 + lane) * 2048 + ko_,                   \
               &lB[b][w * 2048 + sg_ * 512]);                          \
  } while (0)

  GWO_STAGE(0, 0);
  for (int ck = 0; ck < 16; ++ck) {
    const int cur = ck & 1;
    if (ck < 15) {
      GWO_STAGE(ck + 1, cur ^ 1);
      asm volatile("s_waitcnt vmcnt(5)" ::: "memory");
    } else {
      asm volatile("s_waitcnt vmcnt(0)" ::: "memory");
    }
    __builtin_amdgcn_s_barrier();
    asm volatile("" ::: "memory");
    bf16x8 af[4], bfg[4];
#pragma unroll
    for (int mi = 0; mi < 4; ++mi)
      af[mi] = *(const bf16x8*)&lA[cur][quad * 512 + (mi * 16 + lc) * 8];
#pragma unroll
    for (int ni = 0; ni < 4; ++ni) {
      const int cl = w * 64 + ni * 16 + lc;
      bfg[ni] = *(const bf16x8*)&lB[cur][quad * 2048 + cl * 8];
    }
#pragma unroll
    for (int mi = 0; mi < 4; ++mi)
#pragma unroll
      for (int ni = 0; ni < 4; ++ni)
        acc[mi][ni] = __builtin_amdgcn_mfma_f32_16x16x32_bf16(af[mi], bfg[ni], acc[mi][ni], 0, 0, 0);
    asm volatile("s_waitcnt lgkmcnt(0)" ::: "memory");
    __builtin_amdgcn_s_barrier();
  }
#undef GWO_STAGE

  float* O = out + kz * 2097152 + bb * 64 * 256;
#pragma unroll
  for (int mi = 0; mi < 4; ++mi)
#pragma unroll
    for (int ni = 0; ni < 4; ++ni) {
      const int cg = w * 64 + ni * 16 + lc;
#pragma unroll
      for (int r = 0; r < 4; ++r)
        O[(mi * 16 + quad * 4 + r) * 256 + cg] = acc[mi][ni][r];
    }
}

// ---------------- FF GEMM (64x128 tile, K=256, fused bias+resid epilogue) ----------------
__global__ __launch_bounds__(256) void gemm_ff_kernel(
    const u16* __restrict__ A, const u16* __restrict__ BT, const float* __restrict__ bias,
    const u16* __restrict__ residb, float* __restrict__ out)
{
  __shared__ u16 lA[2][2048];
  __shared__ u16 lB[2][4096];
  const int t = threadIdx.x;
  const int w = t >> 6, lane = t & 63, quad = lane >> 4, lc = lane & 15;
  const int tn = blockIdx.x, bb = blockIdx.y;
  const u16* A0 = A + bb * 64 * 256;
  const u16* BT0 = BT + tn * 128 * 256;

  const f32x4 fz = {0.f, 0.f, 0.f, 0.f};
  f32x4 acc[4][2];
#pragma unroll
  for (int i = 0; i < 4; ++i) { acc[i][0] = fz; acc[i][1] = fz; }

#define GFF_STAGE(ck, b) do {                                          \
    const int ko_ = (ck) * 32 + w * 8;                                 \
    gl_lds16(A0 + lane * 256 + ko_,        &lA[b][w * 512]);           \
    gl_lds16(BT0 + lane * 256 + ko_,       &lB[b][w * 1024]);          \
    gl_lds16(BT0 + (64 + lane) * 256 + ko_, &lB[b][w * 1024 + 512]);   \
  } while (0)

  GFF_STAGE(0, 0);
  for (int ck = 0; ck < 8; ++ck) {
    const int cur = ck & 1;
    if (ck < 7) {
      GFF_STAGE(ck + 1, cur ^ 1);
      asm volatile("s_waitcnt vmcnt(3)" ::: "memory");
    } else {
      asm volatile("s_waitcnt vmcnt(0)" ::: "memory");
    }
    __builtin_amdgcn_s_barrier();
    asm volatile("" ::: "memory");
    bf16x8 af[4], bfg[2];
#pragma unroll
    for (int mi = 0; mi < 4; ++mi)
      af[mi] = *(const bf16x8*)&lA[cur][quad * 512 + (mi * 16 + lc) * 8];
#pragma unroll
    for (int ni = 0; ni < 2; ++ni) {
      const int cl = w * 32 + ni * 16 + lc;
      bfg[ni] = *(const bf16x8*)&lB[cur][quad * 1024 + (cl >> 6) * 512 + (cl & 63) * 8];
    }
#pragma unroll
    for (int mi = 0; mi < 4; ++mi)
#pragma unroll
      for (int ni = 0; ni < 2; ++ni)
        acc[mi][ni] = __builtin_amdgcn_mfma_f32_16x16x32_bf16(af[mi], bfg[ni], acc[mi][ni], 0, 0, 0);
    asm volatile("s_waitcnt lgkmcnt(0)" ::: "memory");
    __builtin_amdgcn_s_barrier();
  }
#undef GFF_STAGE

#pragma unroll
  for (int mi = 0; mi < 4; ++mi)
#pragma unroll
    for (int ni = 0; ni < 2; ++ni) {
      const int cg = tn * 128 + w * 32 + ni * 16 + lc;
      const float bi = bias[cg];
#pragma unroll
      for (int r = 0; r < 4; ++r) {
        const int rl = mi * 16 + quad * 4 + r;
        const float res = bf2f(residb[(bb * 64 + rl) * 256 + cg]);
        out[(bb * 64 + rl) * 256 + cg] = acc[mi][ni][r] + bi + res;
      }
    }
}

// ---------------- fused split-K reduce + bias + value-resid + LN1 -> bf16 ----------------
__global__ __launch_bounds__(256) void reduce_ln_kernel(
    const float* __restrict__ part, const float* __restrict__ bias,
    const float* __restrict__ value, const float* __restrict__ gam,
    const float* __restrict__ bet, u16* __restrict__ dstb)
{
  const int t = threadIdx.x, w = t >> 6, lane = t & 63;
  const int row = blockIdx.x * 4 + w;
  const int e = row * 256 + lane * 4;
  const int col = lane * 4;
  f32x4 s = *(const f32x4*)(part + e);
#pragma unroll
  for (int p = 1; p < 4; ++p) {
    const f32x4 v = *(const f32x4*)(part + p * 2097152 + e);
#pragma unroll
    for (int i = 0; i < 4; ++i) s[i] += v[i];
  }
  const f32x4 bi = *(const f32x4*)(bias + col);
  const f32x4 rv = *(const f32x4*)(value + e);
#pragma unroll
  for (int i = 0; i < 4; ++i) s[i] += bi[i] + rv[i];
  float sum = s[0] + s[1] + s[2] + s[3];
  float sq = s[0] * s[0] + s[1] * s[1] + s[2] * s[2] + s[3] * s[3];
#pragma unroll
  for (int m = 1; m < 64; m <<= 1) { sum += __shfl_xor(sum, m); sq += __shfl_xor(sq, m); }
  const float mean = sum * (1.0f / 256.0f);
  const float rs = rsqrtf(sq * (1.0f / 256.0f) - mean * mean + 1e-5f);
  const f32x4 g4 = *(const f32x4*)(gam + col);
  const f32x4 b4 = *(const f32x4*)(bet + col);
  u16x4 ob;
#pragma unroll
  for (int i = 0; i < 4; ++i) ob[i] = f2bf((s[i] - mean) * rs * g4[i] + b4[i]);
  *(u16x4*)(dstb + row * 256 + lane * 4) = ob;
}

// ---------------- final layernorm -> d_out ----------------
__global__ __launch_bounds__(256) void ln2_kernel(
    const float* __restrict__ src, const float* __restrict__ gam, const float* __restrict__ bet,
    float* __restrict__ dstf)
{
  const int t = threadIdx.x, w = t >> 6, lane = t & 63;
  const int row = blockIdx.x * 4 + w;
  const f32x4 v = *(const f32x4*)(src + row * 256 + lane * 4);
  float sum = v[0] + v[1] + v[2] + v[3];
  float sq = v[0] * v[0] + v[1] * v[1] + v[2] * v[2] + v[3] * v[3];
#pragma unroll
  for (int m = 1; m < 64; m <<= 1) { sum += __shfl_xor(sum, m); sq += __shfl_xor(sq, m); }
  const float mean = sum * (1.0f / 256.0f);
  const float rs = rsqrtf(sq * (1.0f / 256.0f) - mean * mean + 1e-5f);
  const f32x4 g4 = *(const f32x4*)(gam + lane * 4);
  const f32x4 b4 = *(const f32x4*)(bet + lane * 4);
  f32x4 o;
#pragma unroll
  for (int i = 0; i < 4; ++i)
    o[i] = (v[i] - mean) * rs * g4[i] + b4[i];
  *(f32x4*)(dstf + row * 256 + lane * 4) = o;
}

extern "C" void kernel_launch(void* const* d_in, const int* in_sizes, int n_in,
                              void* d_out, int out_size, void* d_ws, size_t ws_size,
                              hipStream_t stream) {
  (void)in_sizes; (void)n_in; (void)out_size; (void)ws_size;
  const float* query = (const float*)d_in[0];
  const float* key   = (const float*)d_in[1];
  const float* value = (const float*)d_in[2];
  const float* Wq  = (const float*)d_in[3];
  const float* bq  = (const float*)d_in[4];
  const float* Wk  = (const float*)d_in[5];
  const float* bk  = (const float*)d_in[6];
  const float* Wv  = (const float*)d_in[7];
  const float* bv  = (const float*)d_in[8];
  const float* Wo  = (const float*)d_in[9];
  const float* bo  = (const float*)d_in[10];
  const float* g1  = (const float*)d_in[11];
  const float* b1  = (const float*)d_in[12];
  const float* Wff = (const float*)d_in[13];
  const float* bff = (const float*)d_in[14];
  const float* g2  = (const float*)d_in[15];
  const float* b2  = (const float*)d_in[16];

  u16* ws  = (u16*)d_ws;
  u16* WT  = ws;                      // [0, 2162688)
  u16* qb  = ws + 2162688;            // 2,097,152 each (8192x256 bf16)
  u16* kb  = ws + 4259840;
  u16* vb  = ws + 6356992;
  u16* Pq  = ws + 8454144;            // 16,777,216 each (8192x2048 bf16)
  u16* Pk  = ws + 25231360;
  u16* VT  = ws + 42008576;           // 512 groups x [d=256][q'=128]
  u16* Obuf = ws + 58785792;          // 16,777,216 (linear gathered 8192x2048)
  u16* Pv  = Obuf;                    // same region (dead before attn writes O)
  float* part = (float*)(ws + 8454144);   // 4 x 2,097,152 f32 over Pq+Pk (dead after attn)
  u16* xbuf   = ws + 49872896;            // 2,097,152 u16 within VT region (dead after attn)
  float* tmp2 = (float*)(ws + 42008576);  // 2,097,152 f32 over VT (dead after FF reads xbuf? no - see below)

  // tmp2 placement: VT is dead after attn, but xbuf (49872896) also lives in
  // the VT region. tmp2 needs 8,388,608 B starting at 42008576*2 B; xbuf
  // starts at byte 99745792, tmp2 ends at byte 92405760 -> disjoint. OK.

  convert_kernel<<<dim3(2048, 3), 256, 0, stream>>>(query, key, value, qb, kb, vb);
  transpose_kernel<<<dim3(2048, 5), 256, 0, stream>>>(Wq, Wk, Wv, Wo, Wff, WT);
  proj_kernel<<<dim3(16, 64, 3), 256, 0, stream>>>(qb, kb, vb, WT, bq, bk, bv, Pq, Pk, Pv);
  vtrans_kernel<<<dim3(8, 512), 256, 0, stream>>>(Pv, VT);
  // Dedup'd attention: 512 distinct units, linear gathered output.
  attn_kernel<<<dim3(64, 8), 512, 0, stream>>>(Pq, Pk, VT, Obuf);
  // Wo GEMM on linear rows (M=8192), split-K=4 -> partials.
  gemm_wo_kernel<<<dim3(128, 1, 4), 256, 0, stream>>>(Obuf, WT + 1572864, part);
  reduce_ln_kernel<<<2048, 256, 0, stream>>>(part, bo, value, g1, b1, xbuf);
  gemm_ff_kernel<<<dim3(2, 128), 256, 0, stream>>>(xbuf, WT + 2097152, bff, xbuf, tmp2);
  ln2_kernel<<<2048, 256, 0, stream>>>(tmp2, g2, b2, (float*)d_out);
}